// Round 5
// baseline (789.067 us; speedup 1.0000x reference)
//
#include <hip/hip_runtime.h>
#include <hip/hip_bf16.h>
#include <stdint.h>

#define HID 128
#define NPART 8        // one partition per XCD (blockIdx & 7 -> XCD under round-robin)
#define NCHUNK 256     // chunks per partition; grid = NPART*NCHUNK blocks

// ---------------- mask storage detection ----------------
__global__ void detect_mask_kernel(const unsigned char* __restrict__ p, int nbytes,
                                   int nfloat, int* __restrict__ flags) {
  int stride = blockDim.x * gridDim.x;
  for (int i = blockIdx.x * blockDim.x + threadIdx.x; i < nbytes; i += stride) {
    if ((i & 3) && p[i] != 0) { atomicOr(&flags[0], 1); break; }
  }
  const float* fp = (const float*)p;
  for (int i = blockIdx.x * blockDim.x + threadIdx.x; i < nfloat; i += stride) {
    float f = fp[i];
    if (!(f == 0.0f || f == 1.0f)) { atomicOr(&flags[1], 1); break; }
  }
}

// maskout = mask as 0/1 float; cvec[n][4..7] = h0[n] = mask?x:0; h0s[n] = dis[n]*h0[n]
__global__ void expand_mask_h0(const void* __restrict__ maskp, const float4* __restrict__ x4,
                               const int* __restrict__ flags, const float* __restrict__ dis,
                               float* __restrict__ maskout, float* __restrict__ cvec,
                               float4* __restrict__ h0s, int N) {
  int i = blockIdx.x * blockDim.x + threadIdx.x;
  if (i >= N) return;
  float m;
  if (flags[0] == 0)      m = (((const int*)maskp)[i] != 0) ? 1.f : 0.f;
  else if (flags[1] == 0) m = (((const float*)maskp)[i] != 0.f) ? 1.f : 0.f;
  else                    m = (((const unsigned char*)maskp)[i] != 0) ? 1.f : 0.f;
  maskout[i] = m;
  float4 xv = x4[i];
  float4 h0 = make_float4(m * xv.x, m * xv.y, m * xv.z, m * xv.w);
  float* cv = cvec + (size_t)i * 8;
  cv[4] = h0.x; cv[5] = h0.y; cv[6] = h0.z; cv[7] = h0.w;
  float d = dis[i];
  h0s[i] = make_float4(d * h0.x, d * h0.y, d * h0.z, d * h0.w);
}

// ---------------- CSR build: XCD-partitioned + NT streaming loads ----------------
__global__ void hist_part_kernel(const int* __restrict__ dst, int* __restrict__ cnt,
                                 int E, int N) {
  int p = blockIdx.x & (NPART - 1);
  int chunk = blockIdx.x >> 3;
  int lo = (int)((long long)p * N / NPART);
  int hi = (int)((long long)(p + 1) * N / NPART);
  int stride = NCHUNK * 256;
  for (int e = chunk * 256 + threadIdx.x; e < E; e += stride) {
    int d = __builtin_nontemporal_load(&dst[e]);
    if (d >= lo && d < hi) atomicAdd(&cnt[d], 1);
  }
}

__global__ void fill_part_kernel(const int* __restrict__ src, const int* __restrict__ dst,
                                 int* __restrict__ cur, int* __restrict__ csr, int E, int N) {
  int p = blockIdx.x & (NPART - 1);
  int chunk = blockIdx.x >> 3;
  int lo = (int)((long long)p * N / NPART);
  int hi = (int)((long long)(p + 1) * N / NPART);
  int stride = NCHUNK * 256;
  for (int e = chunk * 256 + threadIdx.x; e < E; e += stride) {
    int d = __builtin_nontemporal_load(&dst[e]);
    if (d >= lo && d < hi) {
      int s = __builtin_nontemporal_load(&src[e]);
      int pos = atomicAdd(&cur[d], 1);
      csr[pos] = s;
    }
  }
}

// ---------------- scan machinery (1024 elements per block); also emits dis ----------------
__global__ void scan1_kernel(const int* __restrict__ cnt, int* __restrict__ off,
                             int* __restrict__ bsum, float* __restrict__ dis, int N) {
  __shared__ int wsum[4];
  int t = threadIdx.x, lane = t & 63, w = t >> 6;
  int base = blockIdx.x * 1024 + t * 4;
  int v0 = (base + 0 < N) ? cnt[base + 0] : 0;
  int v1 = (base + 1 < N) ? cnt[base + 1] : 0;
  int v2 = (base + 2 < N) ? cnt[base + 2] : 0;
  int v3 = (base + 3 < N) ? cnt[base + 3] : 0;
  if (base + 0 < N) dis[base + 0] = rsqrtf((float)v0 + 1.0f);
  if (base + 1 < N) dis[base + 1] = rsqrtf((float)v1 + 1.0f);
  if (base + 2 < N) dis[base + 2] = rsqrtf((float)v2 + 1.0f);
  if (base + 3 < N) dis[base + 3] = rsqrtf((float)v3 + 1.0f);
  int ts = v0 + v1 + v2 + v3;
  int sc = ts;
  for (int d = 1; d < 64; d <<= 1) {
    int x = __shfl_up(sc, d, 64);
    if (lane >= d) sc += x;
  }
  if (lane == 63) wsum[w] = sc;
  __syncthreads();
  int wo = 0;
  for (int i = 0; i < w; i++) wo += wsum[i];
  int excl = wo + sc - ts;
  if (base + 0 < N) off[base + 0] = excl;
  if (base + 1 < N) off[base + 1] = excl + v0;
  if (base + 2 < N) off[base + 2] = excl + v0 + v1;
  if (base + 3 < N) off[base + 3] = excl + v0 + v1 + v2;
  if (t == 255) bsum[blockIdx.x] = wo + sc;
}

__global__ void scan2_kernel(int* __restrict__ bsum, int nb) {
  if (threadIdx.x == 0 && blockIdx.x == 0) {
    int run = 0;
    for (int i = 0; i < nb; i++) { int v = bsum[i]; bsum[i] = run; run += v; }
  }
}

__global__ void scan3_kernel(int* __restrict__ off, const int* __restrict__ bsum,
                             int* __restrict__ cur, int N, int E) {
  int i = blockIdx.x * blockDim.x + threadIdx.x;
  if (i < N) {
    int o = off[i] + bsum[i >> 10];
    off[i] = o;
    cur[i] = o;
  }
  if (i == 0) off[N] = E;
}

// ---------------- layer 0 aggregation (4-dim, pre-scaled operand) ----------------
__global__ void l0_agg_kernel(const float4* __restrict__ h0s, const float* __restrict__ dis,
                              const int* __restrict__ off, const int* __restrict__ csr,
                              float* __restrict__ cvec, int N) {
  int n = blockIdx.x * blockDim.x + threadIdx.x;
  if (n >= N) return;
  float4 a = h0s[n];
  int e0 = off[n], e1 = off[n + 1];
  int i = e0;
  for (; i + 4 <= e1; i += 4) {
    int s0 = __builtin_nontemporal_load(&csr[i]);
    int s1 = __builtin_nontemporal_load(&csr[i + 1]);
    int s2 = __builtin_nontemporal_load(&csr[i + 2]);
    int s3 = __builtin_nontemporal_load(&csr[i + 3]);
    float4 v0 = h0s[s0], v1 = h0s[s1], v2 = h0s[s2], v3 = h0s[s3];
    a.x += v0.x + v1.x + v2.x + v3.x;
    a.y += v0.y + v1.y + v2.y + v3.y;
    a.z += v0.z + v1.z + v2.z + v3.z;
    a.w += v0.w + v1.w + v2.w + v3.w;
  }
  for (; i < e1; i++) {
    float4 v = h0s[__builtin_nontemporal_load(&csr[i])];
    a.x += v.x; a.y += v.y; a.z += v.z; a.w += v.w;
  }
  float dn = dis[n];
  float* cv = cvec + (size_t)n * 8;
  cv[0] = dn * a.x; cv[1] = dn * a.y; cv[2] = dn * a.z; cv[3] = dn * a.w;
}

// h1 = relu(agg0@W0 + b0 + h0@resW + res_b); also hb = bf16(dis*h1)
__global__ void l0_combine_kernel(const float* __restrict__ cvec, const float* __restrict__ W0,
                                  const float* __restrict__ b0, const float* __restrict__ resW,
                                  const float* __restrict__ resb, const float* __restrict__ dis,
                                  float* __restrict__ h1, __hip_bfloat16* __restrict__ hbout) {
  int idx = blockIdx.x * blockDim.x + threadIdx.x;
  int n = idx >> 7, c = idx & 127;
  const float* cv = cvec + (size_t)n * 8;
  float acc = b0[c] + resb[c];
#pragma unroll
  for (int k = 0; k < 4; k++) {
    acc += cv[k] * W0[k * HID + c];
    acc += cv[4 + k] * resW[k * HID + c];
  }
  float v = fmaxf(acc, 0.0f);
  h1[idx] = v;
  if (hbout) hbout[idx] = __float2bfloat16(dis[n] * v);
}

// ---------------- 128-dim aggregation, bf16 pre-scaled uint2 gather ----------------
// Wave per node. Lane = (half = lane>>5, c = lane&31). Lane loads 8B (= channels
// 4c..4c+3) of one src row; halves process alternating edges; shfl_xor(32) combines.
__global__ void agg_hid_bf16_kernel(const uint2* __restrict__ hb2, const float* __restrict__ dis,
                                    const int* __restrict__ off, const int* __restrict__ csr,
                                    float* __restrict__ out, int N) {
  int node = blockIdx.x * 4 + (threadIdx.x >> 6);
  int lane = threadIdx.x & 63;
  if (node >= N) return;
  int half = lane >> 5;
  int c = lane & 31;
  float a0 = 0.f, a1 = 0.f, a2 = 0.f, a3 = 0.f;
  if (half == 0) {  // self term once
    uint2 v = hb2[(size_t)node * 32 + c];
    a0 = __uint_as_float(v.x << 16);
    a1 = __uint_as_float(v.x & 0xffff0000u);
    a2 = __uint_as_float(v.y << 16);
    a3 = __uint_as_float(v.y & 0xffff0000u);
  }
  int e0 = off[node], e1 = off[node + 1];
  int i = e0;
  for (; i + 8 <= e1; i += 8) {
    int s0 = __builtin_nontemporal_load(&csr[i + half]);
    int s1 = __builtin_nontemporal_load(&csr[i + 2 + half]);
    int s2 = __builtin_nontemporal_load(&csr[i + 4 + half]);
    int s3 = __builtin_nontemporal_load(&csr[i + 6 + half]);
    uint2 v0 = hb2[(size_t)s0 * 32 + c];
    uint2 v1 = hb2[(size_t)s1 * 32 + c];
    uint2 v2 = hb2[(size_t)s2 * 32 + c];
    uint2 v3 = hb2[(size_t)s3 * 32 + c];
    a0 += __uint_as_float(v0.x << 16); a1 += __uint_as_float(v0.x & 0xffff0000u);
    a2 += __uint_as_float(v0.y << 16); a3 += __uint_as_float(v0.y & 0xffff0000u);
    a0 += __uint_as_float(v1.x << 16); a1 += __uint_as_float(v1.x & 0xffff0000u);
    a2 += __uint_as_float(v1.y << 16); a3 += __uint_as_float(v1.y & 0xffff0000u);
    a0 += __uint_as_float(v2.x << 16); a1 += __uint_as_float(v2.x & 0xffff0000u);
    a2 += __uint_as_float(v2.y << 16); a3 += __uint_as_float(v2.y & 0xffff0000u);
    a0 += __uint_as_float(v3.x << 16); a1 += __uint_as_float(v3.x & 0xffff0000u);
    a2 += __uint_as_float(v3.y << 16); a3 += __uint_as_float(v3.y & 0xffff0000u);
  }
  for (int e = i + half; e < e1; e += 2) {
    int s = __builtin_nontemporal_load(&csr[e]);
    uint2 v = hb2[(size_t)s * 32 + c];
    a0 += __uint_as_float(v.x << 16); a1 += __uint_as_float(v.x & 0xffff0000u);
    a2 += __uint_as_float(v.y << 16); a3 += __uint_as_float(v.y & 0xffff0000u);
  }
  a0 += __shfl_xor(a0, 32, 64);
  a1 += __shfl_xor(a1, 32, 64);
  a2 += __shfl_xor(a2, 32, 64);
  a3 += __shfl_xor(a3, 32, 64);
  if (half == 0) {
    float dn = dis[node];
    *(float4*)&out[(size_t)node * HID + 4 * c] =
        make_float4(dn * a0, dn * a1, dn * a2, dn * a3);
  }
}

// f32 fallback aggregation (ws too small for bf16 buffer)
__global__ void agg_hid_kernel(const float* __restrict__ h, const float* __restrict__ dis,
                               const int* __restrict__ off, const int* __restrict__ csr,
                               float* __restrict__ out, int N) {
  int node = blockIdx.x * 4 + (threadIdx.x >> 6);
  int lane = threadIdx.x & 63;
  if (node >= N) return;
  float dn = dis[node];
  const float* hrow = h + (size_t)node * HID;
  float a0 = dn * hrow[lane];
  float a1 = dn * hrow[lane + 64];
  int e0 = off[node], e1 = off[node + 1];
  for (int i = e0; i < e1; i++) {
    int s = csr[i];
    float d = dis[s];
    const float* hs = h + (size_t)s * HID;
    a0 += d * hs[lane];
    a1 += d * hs[lane + 64];
  }
  out[(size_t)node * HID + lane] = dn * a0;
  out[(size_t)node * HID + lane + 64] = dn * a1;
}

// ---------------- h_next = relu(agg @ W + b + h_res), in-place over agg ----------------
__global__ void gemm_resid_relu_kernel(float* __restrict__ ag, const float* __restrict__ hres,
                                       const float* __restrict__ W, const float* __restrict__ b,
                                       const float* __restrict__ dis,
                                       __hip_bfloat16* __restrict__ hbout, int N) {
  __shared__ float ash[64 * HID];
  int t = threadIdx.x;
  int n0 = blockIdx.x * 64;
  for (int i = t; i < 64 * HID; i += 256) {
    int gn = n0 + (i >> 7);
    ash[i] = (gn < N) ? ag[(size_t)gn * HID + (i & 127)] : 0.0f;
  }
  __syncthreads();
  int tc = t & 31;
  int tn = t >> 5;
  float acc[8][4];
#pragma unroll
  for (int j = 0; j < 8; j++)
#pragma unroll
    for (int q = 0; q < 4; q++) acc[j][q] = 0.0f;

  for (int k = 0; k < HID; k += 4) {
    float4 w0 = *(const float4*)&W[(k + 0) * HID + tc * 4];
    float4 w1 = *(const float4*)&W[(k + 1) * HID + tc * 4];
    float4 w2 = *(const float4*)&W[(k + 2) * HID + tc * 4];
    float4 w3 = *(const float4*)&W[(k + 3) * HID + tc * 4];
#pragma unroll
    for (int j = 0; j < 8; j++) {
      float4 a = *(const float4*)&ash[(tn * 8 + j) * HID + k];
      acc[j][0] += a.x * w0.x + a.y * w1.x + a.z * w2.x + a.w * w3.x;
      acc[j][1] += a.x * w0.y + a.y * w1.y + a.z * w2.y + a.w * w3.y;
      acc[j][2] += a.x * w0.z + a.y * w1.z + a.z * w2.z + a.w * w3.z;
      acc[j][3] += a.x * w0.w + a.y * w1.w + a.z * w2.w + a.w * w3.w;
    }
  }
  float4 bv = *(const float4*)&b[tc * 4];
#pragma unroll
  for (int j = 0; j < 8; j++) {
    int gn = n0 + tn * 8 + j;
    if (gn < N) {
      float4 hv = *(const float4*)&hres[(size_t)gn * HID + tc * 4];
      float4 o;
      o.x = fmaxf(acc[j][0] + bv.x + hv.x, 0.0f);
      o.y = fmaxf(acc[j][1] + bv.y + hv.y, 0.0f);
      o.z = fmaxf(acc[j][2] + bv.z + hv.z, 0.0f);
      o.w = fmaxf(acc[j][3] + bv.w + hv.w, 0.0f);
      *(float4*)&ag[(size_t)gn * HID + tc * 4] = o;
      if (hbout) {
        float dnn = dis[gn];
        __hip_bfloat162 p01 = __float22bfloat162_rn(make_float2(dnn * o.x, dnn * o.y));
        __hip_bfloat162 p23 = __float22bfloat162_rn(make_float2(dnn * o.z, dnn * o.w));
        *(__hip_bfloat162*)&hbout[(size_t)gn * HID + tc * 4] = p01;
        *(__hip_bfloat162*)&hbout[(size_t)gn * HID + tc * 4 + 2] = p23;
      }
    }
  }
}

// ---------------- final fc ----------------
__global__ void fc_kernel(const float* __restrict__ h3, const float* __restrict__ fcW,
                          const float* __restrict__ fcb, float* __restrict__ out, int N) {
  __shared__ float sh[64 * 130];
  int t = threadIdx.x;
  int n0 = blockIdx.x * 64;
  for (int i = t; i < 64 * HID; i += 256) {
    int n = i >> 7, k = i & 127;
    int gn = n0 + n;
    sh[n * 130 + k] = (gn < N) ? h3[(size_t)gn * HID + k] : 0.0f;
  }
  __syncthreads();
  int nl = t >> 2, j = t & 3;
  float acc = fcb[j];
  for (int k = 0; k < HID; k++) acc += sh[nl * 130 + k] * fcW[k * 4 + j];
  int gn = n0 + nl;
  if (gn < N) out[(size_t)gn * 4 + j] = acc;
}

// ---------------- host ----------------
extern "C" void kernel_launch(void* const* d_in, const int* in_sizes, int n_in,
                              void* d_out, int out_size, void* d_ws, size_t ws_size,
                              hipStream_t stream) {
  const float* x = (const float*)d_in[0];
  const int* edge = (const int*)d_in[1];
  const void* maskp = d_in[2];
  const float* W0 = (const float*)d_in[3];
  const float* b0 = (const float*)d_in[4];
  const float* resW = (const float*)d_in[5];
  const float* resb = (const float*)d_in[6];
  const float* W1 = (const float*)d_in[7];
  const float* b1 = (const float*)d_in[8];
  const float* W2 = (const float*)d_in[9];
  const float* b2 = (const float*)d_in[10];
  const float* fcW = (const float*)d_in[11];
  const float* fcb = (const float*)d_in[12];
  float* out = (float*)d_out;

  int N = in_sizes[0] / 4;
  int E = in_sizes[1] / 2;
  const int* srcp = edge;
  const int* dstp = edge + E;

  char* ws = (char*)d_ws;
  size_t cursor = 0;
  auto alloc = [&](size_t bytes) { char* p = ws + cursor; cursor += (bytes + 511) & ~(size_t)511; return p; };
  int* flags = (int*)alloc(16);
  int* cnt = (int*)alloc((size_t)N * 4);   // reused as `cur` after scan1
  float* dis = (float*)alloc((size_t)N * 4);
  int* off = (int*)alloc((size_t)(N + 1) * 4);
  int* bsum = (int*)alloc(1024);
  int* csr = (int*)alloc((size_t)E * 4);
  float* h0s = (float*)alloc((size_t)N * 4 * 4);
  float* cvec = (float*)alloc((size_t)N * 8 * 4);
  float* buf0 = (float*)alloc((size_t)N * HID * 4);
  float* buf1 = (float*)alloc((size_t)N * HID * 4);
  size_t base_cursor = cursor;
  __hip_bfloat16* hb = (__hip_bfloat16*)alloc((size_t)N * HID * 2);
  bool use_bf16 = (cursor <= ws_size);
  if (!use_bf16) {
    hb = nullptr;
    if (base_cursor > ws_size) return;
  }

  // zero flags + cnt (adjacent at ws start)
  size_t zbytes = (char*)(cnt + N) - ws;
  hipMemsetAsync(d_ws, 0, zbytes, stream);

  int nThreadsN = (N + 255) / 256;
  int nb = (N + 1023) / 1024;
  int* cur = cnt;  // cnt dead after scan1

  detect_mask_kernel<<<256, 256, 0, stream>>>((const unsigned char*)maskp, N, N / 4, flags);
  hist_part_kernel<<<NPART * NCHUNK, 256, 0, stream>>>(dstp, cnt, E, N);
  scan1_kernel<<<nb, 256, 0, stream>>>(cnt, off, bsum, dis, N);
  scan2_kernel<<<1, 64, 0, stream>>>(bsum, nb);
  scan3_kernel<<<nThreadsN, 256, 0, stream>>>(off, bsum, cur, N, E);
  fill_part_kernel<<<NPART * NCHUNK, 256, 0, stream>>>(srcp, dstp, cur, csr, E, N);

  expand_mask_h0<<<nThreadsN, 256, 0, stream>>>(maskp, (const float4*)x, flags, dis,
                                                out + (size_t)N * 4, cvec, (float4*)h0s, N);

  // layer 0
  l0_agg_kernel<<<nThreadsN, 256, 0, stream>>>((const float4*)h0s, dis, off, csr, cvec, N);
  l0_combine_kernel<<<(N * HID + 255) / 256, 256, 0, stream>>>(cvec, W0, b0, resW, resb, dis,
                                                               buf0, hb);

  // layer 1: agg(h1) -> buf1 ; h2 = relu(buf1@W1 + b1 + buf0) -> buf1 (+ hb)
  if (use_bf16)
    agg_hid_bf16_kernel<<<(N + 3) / 4, 256, 0, stream>>>((const uint2*)hb, dis, off, csr, buf1, N);
  else
    agg_hid_kernel<<<(N + 3) / 4, 256, 0, stream>>>(buf0, dis, off, csr, buf1, N);
  gemm_resid_relu_kernel<<<(N + 63) / 64, 256, 0, stream>>>(buf1, buf0, W1, b1, dis, hb, N);

  // layer 2: agg(h2) -> buf0 ; h3 = relu(buf0@W2 + b2 + buf1) -> buf0
  if (use_bf16)
    agg_hid_bf16_kernel<<<(N + 3) / 4, 256, 0, stream>>>((const uint2*)hb, dis, off, csr, buf0, N);
  else
    agg_hid_kernel<<<(N + 3) / 4, 256, 0, stream>>>(buf1, dis, off, csr, buf0, N);
  gemm_resid_relu_kernel<<<(N + 63) / 64, 256, 0, stream>>>(buf0, buf1, W2, b2, dis, nullptr, N);

  // output
  fc_kernel<<<(N + 63) / 64, 256, 0, stream>>>(buf0, fcW, fcb, out, N);
}

// Round 6
// 673.894 us; speedup vs baseline: 1.1709x; 1.1709x over previous
//
#include <hip/hip_runtime.h>
#include <hip/hip_bf16.h>
#include <stdint.h>

#define HID 128
#define NPART 8        // sub-region classes (blockIdx&7 -> XCD under round-robin)
#define NCHUNK 256

// ---------------- mask storage detection ----------------
__global__ void detect_mask_kernel(const unsigned char* __restrict__ p, int nbytes,
                                   int nfloat, int* __restrict__ flags) {
  int stride = blockDim.x * gridDim.x;
  for (int i = blockIdx.x * blockDim.x + threadIdx.x; i < nbytes; i += stride) {
    if ((i & 3) && p[i] != 0) { atomicOr(&flags[0], 1); break; }
  }
  const float* fp = (const float*)p;
  for (int i = blockIdx.x * blockDim.x + threadIdx.x; i < nfloat; i += stride) {
    float f = fp[i];
    if (!(f == 0.0f || f == 1.0f)) { atomicOr(&flags[1], 1); break; }
  }
}

// maskout = mask as 0/1 float; cvec[n][4..7] = h0[n] = mask?x:0; h0s[n] = dis[n]*h0[n]
__global__ void expand_mask_h0(const void* __restrict__ maskp, const float4* __restrict__ x4,
                               const int* __restrict__ flags, const float* __restrict__ dis,
                               float* __restrict__ maskout, float* __restrict__ cvec,
                               float4* __restrict__ h0s, int N) {
  int i = blockIdx.x * blockDim.x + threadIdx.x;
  if (i >= N) return;
  float m;
  if (flags[0] == 0)      m = (((const int*)maskp)[i] != 0) ? 1.f : 0.f;
  else if (flags[1] == 0) m = (((const float*)maskp)[i] != 0.f) ? 1.f : 0.f;
  else                    m = (((const unsigned char*)maskp)[i] != 0) ? 1.f : 0.f;
  maskout[i] = m;
  float4 xv = x4[i];
  float4 h0 = make_float4(m * xv.x, m * xv.y, m * xv.z, m * xv.w);
  float* cv = cvec + (size_t)i * 8;
  cv[4] = h0.x; cv[5] = h0.y; cv[6] = h0.z; cv[7] = h0.w;
  float d = dis[i];
  h0s[i] = make_float4(d * h0.x, d * h0.y, d * h0.z, d * h0.w);
}

// ---------------- CSR build: single-pass XCD-clean bucket scatter ----------------
// bucket b = dst>>6; sub-region (b, x=blockIdx&7) at bdata[(b*8+x)*CAP .. +CAP).
// Each sub-region is written only by blocks with the same blockIdx&7 (one XCD
// under round-robin) and fills monotonically -> lines coalesce in that L2.
__global__ void init_bcur_kernel(int* __restrict__ bcur, int n, int CAP) {
  int i = blockIdx.x * blockDim.x + threadIdx.x;
  if (i < n) bcur[i] = i * CAP;
}

__global__ void bucket_scatter_kernel(const int* __restrict__ src, const int* __restrict__ dst,
                                      int* __restrict__ bcur, uint32_t* __restrict__ bdata,
                                      int CAP, int E) {
  int x = blockIdx.x & (NPART - 1);
  int stride = gridDim.x * blockDim.x;
  for (int e = blockIdx.x * blockDim.x + threadIdx.x; e < E; e += stride) {
    int d = __builtin_nontemporal_load(&dst[e]);
    int s = __builtin_nontemporal_load(&src[e]);
    int r = (d >> 6) * NPART + x;
    int pos = atomicAdd(&bcur[r], 1);
    if (pos < (r + 1) * CAP)  // capacity guard (statistically never hit)
      bdata[pos] = ((uint32_t)(d & 63) << 26) | (uint32_t)s;
  }
}

// per-bucket totals (clamped to capacity, consistent with entries present)
__global__ void btot_kernel(const int* __restrict__ bcur, int* __restrict__ btot,
                            int nbuckets, int CAP) {
  int b = blockIdx.x * blockDim.x + threadIdx.x;
  if (b >= nbuckets) return;
  int tot = 0;
#pragma unroll
  for (int x = 0; x < NPART; x++) {
    int r = b * NPART + x;
    int c = bcur[r] - r * CAP;
    tot += (c > CAP) ? CAP : c;
  }
  btot[b] = tot;
}

// per-bucket LDS counting sort: emits csr (globally dst-sorted), off[], dis[]
__global__ void bucket_sort_kernel(const uint32_t* __restrict__ bdata,
                                   const int* __restrict__ bcur,
                                   const int* __restrict__ bstart, int CAP,
                                   int* __restrict__ off, float* __restrict__ dis,
                                   int* __restrict__ csr, int N, int E) {
  __shared__ int cnt_l[64], off_l[64], pos_l[64];
  int b = blockIdx.x, t = threadIdx.x;
  int bb = bstart[b];
  if (t < 64) { cnt_l[t] = 0; pos_l[t] = 0; }
  __syncthreads();
#pragma unroll
  for (int x = 0; x < NPART; x++) {
    int r = b * NPART + x;
    int c = bcur[r] - r * CAP;
    int cntx = (c > CAP) ? CAP : c;
    for (int i = t; i < cntx; i += 256) atomicAdd(&cnt_l[bdata[r * CAP + i] >> 26], 1);
  }
  __syncthreads();
  if (t < 64) {
    int c = cnt_l[t];
    int sc = c;
    for (int d = 1; d < 64; d <<= 1) {
      int v = __shfl_up(sc, d, 64);
      if (t >= d) sc += v;
    }
    int excl = sc - c;
    off_l[t] = excl;
    int dstn = b * 64 + t;
    if (dstn < N) {
      off[dstn] = bb + excl;
      dis[dstn] = rsqrtf((float)c + 1.0f);
    }
  }
  if (b == 0 && t == 255) off[N] = E;
  __syncthreads();
#pragma unroll
  for (int x = 0; x < NPART; x++) {
    int r = b * NPART + x;
    int c = bcur[r] - r * CAP;
    int cntx = (c > CAP) ? CAP : c;
    for (int i = t; i < cntx; i += 256) {
      uint32_t v = bdata[r * CAP + i];
      int dl = v >> 26;
      int p = atomicAdd(&pos_l[dl], 1);
      csr[bb + off_l[dl] + p] = (int)(v & 0x03FFFFFFu);
    }
  }
}

// ---------------- scan machinery (1024 elements per block) ----------------
__global__ void scan1_kernel(const int* __restrict__ cnt, int* __restrict__ off,
                             int* __restrict__ bsum, float* __restrict__ dis, int N) {
  __shared__ int wsum[4];
  int t = threadIdx.x, lane = t & 63, w = t >> 6;
  int base = blockIdx.x * 1024 + t * 4;
  int v0 = (base + 0 < N) ? cnt[base + 0] : 0;
  int v1 = (base + 1 < N) ? cnt[base + 1] : 0;
  int v2 = (base + 2 < N) ? cnt[base + 2] : 0;
  int v3 = (base + 3 < N) ? cnt[base + 3] : 0;
  if (dis) {
    if (base + 0 < N) dis[base + 0] = rsqrtf((float)v0 + 1.0f);
    if (base + 1 < N) dis[base + 1] = rsqrtf((float)v1 + 1.0f);
    if (base + 2 < N) dis[base + 2] = rsqrtf((float)v2 + 1.0f);
    if (base + 3 < N) dis[base + 3] = rsqrtf((float)v3 + 1.0f);
  }
  int ts = v0 + v1 + v2 + v3;
  int sc = ts;
  for (int d = 1; d < 64; d <<= 1) {
    int x = __shfl_up(sc, d, 64);
    if (lane >= d) sc += x;
  }
  if (lane == 63) wsum[w] = sc;
  __syncthreads();
  int wo = 0;
  for (int i = 0; i < w; i++) wo += wsum[i];
  int excl = wo + sc - ts;
  if (base + 0 < N) off[base + 0] = excl;
  if (base + 1 < N) off[base + 1] = excl + v0;
  if (base + 2 < N) off[base + 2] = excl + v0 + v1;
  if (base + 3 < N) off[base + 3] = excl + v0 + v1 + v2;
  if (t == 255) bsum[blockIdx.x] = wo + sc;
}

__global__ void scan2_kernel(int* __restrict__ bsum, int nb) {
  if (threadIdx.x == 0 && blockIdx.x == 0) {
    int run = 0;
    for (int i = 0; i < nb; i++) { int v = bsum[i]; bsum[i] = run; run += v; }
  }
}

__global__ void scan3_kernel(int* __restrict__ off, const int* __restrict__ bsum,
                             int* __restrict__ cur, int N, int E) {
  int i = blockIdx.x * blockDim.x + threadIdx.x;
  if (i < N) {
    int o = off[i] + bsum[i >> 10];
    off[i] = o;
    if (cur) cur[i] = o;
  }
  if (i == 0) off[N] = E;
}

// ---------------- fallback CSR build (N > 2^26 or ws-limited) ----------------
__global__ void hist_part_kernel(const int* __restrict__ dst, int* __restrict__ cnt,
                                 int E, int N) {
  int p = blockIdx.x & (NPART - 1);
  int chunk = blockIdx.x >> 3;
  int lo = (int)((long long)p * N / NPART);
  int hi = (int)((long long)(p + 1) * N / NPART);
  int stride = NCHUNK * 256;
  for (int e = chunk * 256 + threadIdx.x; e < E; e += stride) {
    int d = __builtin_nontemporal_load(&dst[e]);
    if (d >= lo && d < hi) atomicAdd(&cnt[d], 1);
  }
}

__global__ void fill_part_kernel(const int* __restrict__ src, const int* __restrict__ dst,
                                 int* __restrict__ cur, int* __restrict__ csr, int E, int N) {
  int p = blockIdx.x & (NPART - 1);
  int chunk = blockIdx.x >> 3;
  int lo = (int)((long long)p * N / NPART);
  int hi = (int)((long long)(p + 1) * N / NPART);
  int stride = NCHUNK * 256;
  for (int e = chunk * 256 + threadIdx.x; e < E; e += stride) {
    int d = __builtin_nontemporal_load(&dst[e]);
    if (d >= lo && d < hi) {
      int s = __builtin_nontemporal_load(&src[e]);
      int pos = atomicAdd(&cur[d], 1);
      csr[pos] = s;
    }
  }
}

// ---------------- layer 0 aggregation (4-dim, pre-scaled operand) ----------------
__global__ void l0_agg_kernel(const float4* __restrict__ h0s, const float* __restrict__ dis,
                              const int* __restrict__ off, const int* __restrict__ csr,
                              float* __restrict__ cvec, int N) {
  int n = blockIdx.x * blockDim.x + threadIdx.x;
  if (n >= N) return;
  float4 a = h0s[n];
  int e0 = off[n], e1 = off[n + 1];
  int i = e0;
  for (; i + 4 <= e1; i += 4) {
    int s0 = csr[i], s1 = csr[i + 1], s2 = csr[i + 2], s3 = csr[i + 3];
    float4 v0 = h0s[s0], v1 = h0s[s1], v2 = h0s[s2], v3 = h0s[s3];
    a.x += v0.x + v1.x + v2.x + v3.x;
    a.y += v0.y + v1.y + v2.y + v3.y;
    a.z += v0.z + v1.z + v2.z + v3.z;
    a.w += v0.w + v1.w + v2.w + v3.w;
  }
  for (; i < e1; i++) {
    float4 v = h0s[csr[i]];
    a.x += v.x; a.y += v.y; a.z += v.z; a.w += v.w;
  }
  float dn = dis[n];
  float* cv = cvec + (size_t)n * 8;
  cv[0] = dn * a.x; cv[1] = dn * a.y; cv[2] = dn * a.z; cv[3] = dn * a.w;
}

// h1 = relu(agg0@W0 + b0 + h0@resW + res_b); also hb = bf16(dis*h1)
__global__ void l0_combine_kernel(const float* __restrict__ cvec, const float* __restrict__ W0,
                                  const float* __restrict__ b0, const float* __restrict__ resW,
                                  const float* __restrict__ resb, const float* __restrict__ dis,
                                  float* __restrict__ h1, __hip_bfloat16* __restrict__ hbout) {
  int idx = blockIdx.x * blockDim.x + threadIdx.x;
  int n = idx >> 7, c = idx & 127;
  const float* cv = cvec + (size_t)n * 8;
  float acc = b0[c] + resb[c];
#pragma unroll
  for (int k = 0; k < 4; k++) {
    acc += cv[k] * W0[k * HID + c];
    acc += cv[4 + k] * resW[k * HID + c];
  }
  float v = fmaxf(acc, 0.0f);
  h1[idx] = v;
  if (hbout) hbout[idx] = __float2bfloat16(dis[n] * v);
}

// ---------------- 128-dim aggregation, bf16 pre-scaled gather (round-4 form) ----------------
__global__ void agg_hid_bf16_kernel(const uint32_t* __restrict__ hb, const float* __restrict__ dis,
                                    const int* __restrict__ off, const int* __restrict__ csr,
                                    float* __restrict__ out, int N) {
  int node = blockIdx.x * 4 + (threadIdx.x >> 6);
  int lane = threadIdx.x & 63;
  if (node >= N) return;
  uint32_t w = hb[(size_t)node * 64 + lane];
  float a0 = __uint_as_float(w << 16);
  float a1 = __uint_as_float(w & 0xffff0000u);
  int e0 = off[node], e1 = off[node + 1];
  int i = e0;
  for (; i + 4 <= e1; i += 4) {
    int s0 = csr[i], s1 = csr[i + 1], s2 = csr[i + 2], s3 = csr[i + 3];
    uint32_t w0 = hb[(size_t)s0 * 64 + lane];
    uint32_t w1 = hb[(size_t)s1 * 64 + lane];
    uint32_t w2 = hb[(size_t)s2 * 64 + lane];
    uint32_t w3 = hb[(size_t)s3 * 64 + lane];
    a0 += __uint_as_float(w0 << 16);  a1 += __uint_as_float(w0 & 0xffff0000u);
    a0 += __uint_as_float(w1 << 16);  a1 += __uint_as_float(w1 & 0xffff0000u);
    a0 += __uint_as_float(w2 << 16);  a1 += __uint_as_float(w2 & 0xffff0000u);
    a0 += __uint_as_float(w3 << 16);  a1 += __uint_as_float(w3 & 0xffff0000u);
  }
  for (; i < e1; i++) {
    uint32_t ww = hb[(size_t)csr[i] * 64 + lane];
    a0 += __uint_as_float(ww << 16);
    a1 += __uint_as_float(ww & 0xffff0000u);
  }
  float dn = dis[node];
  *(float2*)&out[(size_t)node * HID + 2 * lane] = make_float2(dn * a0, dn * a1);
}

// f32 fallback aggregation (ws too small for bf16 buffer)
__global__ void agg_hid_kernel(const float* __restrict__ h, const float* __restrict__ dis,
                               const int* __restrict__ off, const int* __restrict__ csr,
                               float* __restrict__ out, int N) {
  int node = blockIdx.x * 4 + (threadIdx.x >> 6);
  int lane = threadIdx.x & 63;
  if (node >= N) return;
  float dn = dis[node];
  const float* hrow = h + (size_t)node * HID;
  float a0 = dn * hrow[lane];
  float a1 = dn * hrow[lane + 64];
  int e0 = off[node], e1 = off[node + 1];
  for (int i = e0; i < e1; i++) {
    int s = csr[i];
    float d = dis[s];
    const float* hs = h + (size_t)s * HID;
    a0 += d * hs[lane];
    a1 += d * hs[lane + 64];
  }
  out[(size_t)node * HID + lane] = dn * a0;
  out[(size_t)node * HID + lane + 64] = dn * a1;
}

// ---------------- h_next = relu(agg @ W + b + h_res), in-place over agg ----------------
__global__ void gemm_resid_relu_kernel(float* __restrict__ ag, const float* __restrict__ hres,
                                       const float* __restrict__ W, const float* __restrict__ b,
                                       const float* __restrict__ dis,
                                       __hip_bfloat16* __restrict__ hbout, int N) {
  __shared__ float ash[64 * HID];
  int t = threadIdx.x;
  int n0 = blockIdx.x * 64;
  for (int i = t; i < 64 * HID; i += 256) {
    int gn = n0 + (i >> 7);
    ash[i] = (gn < N) ? ag[(size_t)gn * HID + (i & 127)] : 0.0f;
  }
  __syncthreads();
  int tc = t & 31;
  int tn = t >> 5;
  float acc[8][4];
#pragma unroll
  for (int j = 0; j < 8; j++)
#pragma unroll
    for (int q = 0; q < 4; q++) acc[j][q] = 0.0f;

  for (int k = 0; k < HID; k += 4) {
    float4 w0 = *(const float4*)&W[(k + 0) * HID + tc * 4];
    float4 w1 = *(const float4*)&W[(k + 1) * HID + tc * 4];
    float4 w2 = *(const float4*)&W[(k + 2) * HID + tc * 4];
    float4 w3 = *(const float4*)&W[(k + 3) * HID + tc * 4];
#pragma unroll
    for (int j = 0; j < 8; j++) {
      float4 a = *(const float4*)&ash[(tn * 8 + j) * HID + k];
      acc[j][0] += a.x * w0.x + a.y * w1.x + a.z * w2.x + a.w * w3.x;
      acc[j][1] += a.x * w0.y + a.y * w1.y + a.z * w2.y + a.w * w3.y;
      acc[j][2] += a.x * w0.z + a.y * w1.z + a.z * w2.z + a.w * w3.z;
      acc[j][3] += a.x * w0.w + a.y * w1.w + a.z * w2.w + a.w * w3.w;
    }
  }
  float4 bv = *(const float4*)&b[tc * 4];
#pragma unroll
  for (int j = 0; j < 8; j++) {
    int gn = n0 + tn * 8 + j;
    if (gn < N) {
      float4 hv = *(const float4*)&hres[(size_t)gn * HID + tc * 4];
      float4 o;
      o.x = fmaxf(acc[j][0] + bv.x + hv.x, 0.0f);
      o.y = fmaxf(acc[j][1] + bv.y + hv.y, 0.0f);
      o.z = fmaxf(acc[j][2] + bv.z + hv.z, 0.0f);
      o.w = fmaxf(acc[j][3] + bv.w + hv.w, 0.0f);
      *(float4*)&ag[(size_t)gn * HID + tc * 4] = o;
      if (hbout) {
        float dnn = dis[gn];
        __hip_bfloat162 p01 = __float22bfloat162_rn(make_float2(dnn * o.x, dnn * o.y));
        __hip_bfloat162 p23 = __float22bfloat162_rn(make_float2(dnn * o.z, dnn * o.w));
        *(__hip_bfloat162*)&hbout[(size_t)gn * HID + tc * 4] = p01;
        *(__hip_bfloat162*)&hbout[(size_t)gn * HID + tc * 4 + 2] = p23;
      }
    }
  }
}

// ---------------- final fc ----------------
__global__ void fc_kernel(const float* __restrict__ h3, const float* __restrict__ fcW,
                          const float* __restrict__ fcb, float* __restrict__ out, int N) {
  __shared__ float sh[64 * 130];
  int t = threadIdx.x;
  int n0 = blockIdx.x * 64;
  for (int i = t; i < 64 * HID; i += 256) {
    int n = i >> 7, k = i & 127;
    int gn = n0 + n;
    sh[n * 130 + k] = (gn < N) ? h3[(size_t)gn * HID + k] : 0.0f;
  }
  __syncthreads();
  int nl = t >> 2, j = t & 3;
  float acc = fcb[j];
  for (int k = 0; k < HID; k++) acc += sh[nl * 130 + k] * fcW[k * 4 + j];
  int gn = n0 + nl;
  if (gn < N) out[(size_t)gn * 4 + j] = acc;
}

// ---------------- host ----------------
extern "C" void kernel_launch(void* const* d_in, const int* in_sizes, int n_in,
                              void* d_out, int out_size, void* d_ws, size_t ws_size,
                              hipStream_t stream) {
  const float* x = (const float*)d_in[0];
  const int* edge = (const int*)d_in[1];
  const void* maskp = d_in[2];
  const float* W0 = (const float*)d_in[3];
  const float* b0 = (const float*)d_in[4];
  const float* resW = (const float*)d_in[5];
  const float* resb = (const float*)d_in[6];
  const float* W1 = (const float*)d_in[7];
  const float* b1 = (const float*)d_in[8];
  const float* W2 = (const float*)d_in[9];
  const float* b2 = (const float*)d_in[10];
  const float* fcW = (const float*)d_in[11];
  const float* fcb = (const float*)d_in[12];
  float* out = (float*)d_out;

  int N = in_sizes[0] / 4;
  int E = in_sizes[1] / 2;
  const int* srcp = edge;
  const int* dstp = edge + E;

  char* ws = (char*)d_ws;
  size_t cursor = 0;
  auto alloc = [&](size_t bytes) { char* p = ws + cursor; cursor += (bytes + 511) & ~(size_t)511; return p; };
  int* flags = (int*)alloc(16);
  int* cnt = (int*)alloc((size_t)N * 4);   // fallback path only (alias cur)
  float* dis = (float*)alloc((size_t)N * 4);
  int* off = (int*)alloc((size_t)(N + 1) * 4);
  int* bsum = (int*)alloc(1024);
  int nbuckets = (N + 63) >> 6;
  int* bcur = (int*)alloc((size_t)nbuckets * NPART * 4);
  int* btot = (int*)alloc((size_t)(nbuckets + 1) * 4);
  int* bstart = (int*)alloc((size_t)(nbuckets + 1) * 4);
  int* csr = (int*)alloc((size_t)E * 4);
  float* h0s = (float*)alloc((size_t)N * 4 * 4);
  float* cvec = (float*)alloc((size_t)N * 8 * 4);
  float* buf0 = (float*)alloc((size_t)N * HID * 4);
  float* buf1 = (float*)alloc((size_t)N * HID * 4);
  size_t base_cursor = cursor;
  __hip_bfloat16* hb = (__hip_bfloat16*)alloc((size_t)N * HID * 2);
  bool use_bf16 = (cursor <= ws_size);
  if (!use_bf16) {
    hb = nullptr;
    if (base_cursor > ws_size) return;
  }

  // bucket staging capacity: 2x expected load per (bucket, class), min 256, mult of 64
  long long expect = (long long)E / ((long long)nbuckets * NPART);
  int CAP = (int)(((2 * expect + 63) / 64) * 64);
  if (CAP < 256) CAP = 256;
  size_t bdata_bytes = (size_t)nbuckets * NPART * CAP * 4;
  bool use_bucket = (N <= (1 << 26)) && (bdata_bytes <= (size_t)N * HID * 4);
  uint32_t* bdata = (uint32_t*)buf1;  // staging aliases buf1 (dead until layer-1 agg)

  int nThreadsN = (N + 255) / 256;

  hipMemsetAsync(flags, 0, 16, stream);
  detect_mask_kernel<<<256, 256, 0, stream>>>((const unsigned char*)maskp, N, N / 4, flags);

  if (use_bucket) {
    int nbx = nbuckets * NPART;
    init_bcur_kernel<<<(nbx + 255) / 256, 256, 0, stream>>>(bcur, nbx, CAP);
    bucket_scatter_kernel<<<2048, 256, 0, stream>>>(srcp, dstp, bcur, bdata, CAP, E);
    btot_kernel<<<(nbuckets + 255) / 256, 256, 0, stream>>>(bcur, btot, nbuckets, CAP);
    int nb2 = (nbuckets + 1023) / 1024;
    scan1_kernel<<<nb2, 256, 0, stream>>>(btot, bstart, bsum, nullptr, nbuckets);
    scan2_kernel<<<1, 64, 0, stream>>>(bsum, nb2);
    scan3_kernel<<<(nbuckets + 255) / 256, 256, 0, stream>>>(bstart, bsum, nullptr, nbuckets, E);
    bucket_sort_kernel<<<nbuckets, 256, 0, stream>>>(bdata, bcur, bstart, CAP, off, dis, csr, N, E);
  } else {
    hipMemsetAsync(cnt, 0, (size_t)N * 4, stream);
    int nb = (N + 1023) / 1024;
    hist_part_kernel<<<NPART * NCHUNK, 256, 0, stream>>>(dstp, cnt, E, N);
    scan1_kernel<<<nb, 256, 0, stream>>>(cnt, off, bsum, dis, N);
    scan2_kernel<<<1, 64, 0, stream>>>(bsum, nb);
    scan3_kernel<<<nThreadsN, 256, 0, stream>>>(off, bsum, cnt, N, E);
    fill_part_kernel<<<NPART * NCHUNK, 256, 0, stream>>>(srcp, dstp, cnt, csr, E, N);
  }

  expand_mask_h0<<<nThreadsN, 256, 0, stream>>>(maskp, (const float4*)x, flags, dis,
                                                out + (size_t)N * 4, cvec, (float4*)h0s, N);

  // layer 0
  l0_agg_kernel<<<nThreadsN, 256, 0, stream>>>((const float4*)h0s, dis, off, csr, cvec, N);
  l0_combine_kernel<<<(N * HID + 255) / 256, 256, 0, stream>>>(cvec, W0, b0, resW, resb, dis,
                                                               buf0, hb);

  // layer 1: agg(h1) -> buf1 ; h2 = relu(buf1@W1 + b1 + buf0) -> buf1 (+ hb)
  if (use_bf16)
    agg_hid_bf16_kernel<<<(N + 3) / 4, 256, 0, stream>>>((const uint32_t*)hb, dis, off, csr, buf1, N);
  else
    agg_hid_kernel<<<(N + 3) / 4, 256, 0, stream>>>(buf0, dis, off, csr, buf1, N);
  gemm_resid_relu_kernel<<<(N + 63) / 64, 256, 0, stream>>>(buf1, buf0, W1, b1, dis, hb, N);

  // layer 2: agg(h2) -> buf0 ; h3 = relu(buf0@W2 + b2 + buf1) -> buf0
  if (use_bf16)
    agg_hid_bf16_kernel<<<(N + 3) / 4, 256, 0, stream>>>((const uint32_t*)hb, dis, off, csr, buf0, N);
  else
    agg_hid_kernel<<<(N + 3) / 4, 256, 0, stream>>>(buf1, dis, off, csr, buf0, N);
  gemm_resid_relu_kernel<<<(N + 63) / 64, 256, 0, stream>>>(buf0, buf1, W2, b2, dis, nullptr, N);

  // output
  fc_kernel<<<(N + 63) / 64, 256, 0, stream>>>(buf0, fcW, fcb, out, N);
}

// Round 7
// 606.313 us; speedup vs baseline: 1.3014x; 1.1115x over previous
//
#include <hip/hip_runtime.h>
#include <hip/hip_bf16.h>
#include <stdint.h>

#define HID 128
#define NPART 8
#define NCHUNK 256
#define MCHUNK 4096   // edges per radixA block
#define LBITS 10      // local dst bits; bucket = dst>>LBITS, local = dst&1023
#define SBITS 22      // src bits in packed word (N must be <= 1<<22)

// ---------------- mask storage detection ----------------
__global__ void detect_mask_kernel(const unsigned char* __restrict__ p, int nbytes,
                                   int nfloat, int* __restrict__ flags) {
  int stride = blockDim.x * gridDim.x;
  for (int i = blockIdx.x * blockDim.x + threadIdx.x; i < nbytes; i += stride) {
    if ((i & 3) && p[i] != 0) { atomicOr(&flags[0], 1); break; }
  }
  const float* fp = (const float*)p;
  for (int i = blockIdx.x * blockDim.x + threadIdx.x; i < nfloat; i += stride) {
    float f = fp[i];
    if (!(f == 0.0f || f == 1.0f)) { atomicOr(&flags[1], 1); break; }
  }
}

__global__ void expand_mask_h0(const void* __restrict__ maskp, const float4* __restrict__ x4,
                               const int* __restrict__ flags, const float* __restrict__ dis,
                               float* __restrict__ maskout, float* __restrict__ cvec,
                               float4* __restrict__ h0s, int N) {
  int i = blockIdx.x * blockDim.x + threadIdx.x;
  if (i >= N) return;
  float m;
  if (flags[0] == 0)      m = (((const int*)maskp)[i] != 0) ? 1.f : 0.f;
  else if (flags[1] == 0) m = (((const float*)maskp)[i] != 0.f) ? 1.f : 0.f;
  else                    m = (((const unsigned char*)maskp)[i] != 0) ? 1.f : 0.f;
  maskout[i] = m;
  float4 xv = x4[i];
  float4 h0 = make_float4(m * xv.x, m * xv.y, m * xv.z, m * xv.w);
  float* cv = cvec + (size_t)i * 8;
  cv[4] = h0.x; cv[5] = h0.y; cv[6] = h0.z; cv[7] = h0.w;
  float d = dis[i];
  h0s[i] = make_float4(d * h0.x, d * h0.y, d * h0.z, d * h0.w);
}

// ---------------- CSR build: two-pass LDS-staged radix ----------------
__global__ void init_gcur_kernel(int* __restrict__ gcur, int n, int CAPB) {
  int i = blockIdx.x * blockDim.x + threadIdx.x;
  if (i < n) gcur[i] = i * CAPB;
}

// Pass A: per-block LDS counting sort by bucket, contiguous run reservation, coalesced flush.
__global__ void radixA_kernel(const int* __restrict__ src, const int* __restrict__ dst,
                              int* __restrict__ gcur, uint32_t* __restrict__ bdata,
                              int nbin, int CAPB, int E) {
  __shared__ uint32_t sv[MCHUNK];
  __shared__ uint16_t sb[MCHUNK];
  __shared__ int bcnt[1024], boff[1024], gbase[1024];
  __shared__ int wsum[4];
  int t = threadIdx.x;
  int base = blockIdx.x * MCHUNK;
  int m = E - base; if (m > MCHUNK) m = MCHUNK;
  for (int i = t; i < 1024; i += 256) bcnt[i] = 0;
  __syncthreads();
  uint32_t pk[16]; short bn[16];
#pragma unroll
  for (int j = 0; j < 16; j++) {
    int i = base + t + j * 256;
    if (i < base + m) {
      int d = __builtin_nontemporal_load(&dst[i]);
      int s = __builtin_nontemporal_load(&src[i]);
      int b = d >> LBITS;
      pk[j] = ((uint32_t)(d & ((1 << LBITS) - 1)) << SBITS) | (uint32_t)s;
      bn[j] = (short)b;
      atomicAdd(&bcnt[b], 1);
    } else bn[j] = -1;
  }
  __syncthreads();
  // exclusive scan of bcnt[0..1023]
  {
    int lane = t & 63, w = t >> 6, i0 = t * 4;
    int v0 = bcnt[i0], v1 = bcnt[i0 + 1], v2 = bcnt[i0 + 2], v3 = bcnt[i0 + 3];
    int ts = v0 + v1 + v2 + v3, sc = ts;
    for (int d = 1; d < 64; d <<= 1) { int x = __shfl_up(sc, d, 64); if (lane >= d) sc += x; }
    if (lane == 63) wsum[w] = sc;
    __syncthreads();
    int wo = 0;
    for (int k = 0; k < w; k++) wo += wsum[k];
    int excl = wo + sc - ts;
    boff[i0] = excl; boff[i0 + 1] = excl + v0;
    boff[i0 + 2] = excl + v0 + v1; boff[i0 + 3] = excl + v0 + v1 + v2;
  }
  __syncthreads();
  // reserve global runs; reset bcnt as insert cursors
  for (int i = t; i < nbin; i += 256) {
    int c = bcnt[i];
    gbase[i] = c ? atomicAdd(&gcur[i], c) : 0;
  }
  __syncthreads();
  for (int i = t; i < nbin; i += 256) bcnt[i] = boff[i];
  __syncthreads();
#pragma unroll
  for (int j = 0; j < 16; j++) {
    if (bn[j] >= 0) {
      int p = atomicAdd(&bcnt[bn[j]], 1);
      sv[p] = pk[j];
      sb[p] = (uint16_t)bn[j];
    }
  }
  __syncthreads();
  for (int i = t; i < m; i += 256) {
    int b = sb[i];
    int gp = gbase[b] + (i - boff[b]);
    if (gp < (b + 1) * CAPB) bdata[gp] = sv[i];  // capacity guard (stat. never)
  }
}

// per-bucket totals (clamped)
__global__ void btotB_kernel(const int* __restrict__ gcur, int* __restrict__ btot,
                             int nbin, int CAPB) {
  int b = blockIdx.x * blockDim.x + threadIdx.x;
  if (b < nbin) {
    int c = gcur[b] - b * CAPB;
    btot[b] = (c > CAPB) ? CAPB : c;
  }
}

// Pass B: one block per bucket — LDS hist over 1024 local dsts, scan -> off/dis, scatter csr.
__global__ void radixB_kernel(const uint32_t* __restrict__ bdata, const int* __restrict__ gcur,
                              const int* __restrict__ bstart, int CAPB,
                              int* __restrict__ off, float* __restrict__ dis,
                              int* __restrict__ csr, int N, int E) {
  __shared__ int cnt[1024], loff[1024];
  __shared__ int wsum[4];
  int b = blockIdx.x, t = threadIdx.x;
  int cb = gcur[b] - b * CAPB; if (cb > CAPB) cb = CAPB;
  int gb = bstart[b];
  const uint32_t* bd = bdata + (size_t)b * CAPB;
  for (int i = t; i < 1024; i += 256) cnt[i] = 0;
  __syncthreads();
  for (int i = t; i < cb; i += 256) atomicAdd(&cnt[bd[i] >> SBITS], 1);
  __syncthreads();
  {
    int lane = t & 63, w = t >> 6, i0 = t * 4;
    int v0 = cnt[i0], v1 = cnt[i0 + 1], v2 = cnt[i0 + 2], v3 = cnt[i0 + 3];
    int ts = v0 + v1 + v2 + v3, sc = ts;
    for (int d = 1; d < 64; d <<= 1) { int x = __shfl_up(sc, d, 64); if (lane >= d) sc += x; }
    if (lane == 63) wsum[w] = sc;
    __syncthreads();
    int wo = 0;
    for (int k = 0; k < w; k++) wo += wsum[k];
    int e0 = wo + sc - ts;
    int e1 = e0 + v0, e2 = e1 + v1, e3 = e2 + v2;
    loff[i0] = e0; loff[i0 + 1] = e1; loff[i0 + 2] = e2; loff[i0 + 3] = e3;
    int d0 = b * 1024 + i0;
    if (d0 + 0 < N) { off[d0 + 0] = gb + e0; dis[d0 + 0] = rsqrtf((float)v0 + 1.0f); }
    if (d0 + 1 < N) { off[d0 + 1] = gb + e1; dis[d0 + 1] = rsqrtf((float)v1 + 1.0f); }
    if (d0 + 2 < N) { off[d0 + 2] = gb + e2; dis[d0 + 2] = rsqrtf((float)v2 + 1.0f); }
    if (d0 + 3 < N) { off[d0 + 3] = gb + e3; dis[d0 + 3] = rsqrtf((float)v3 + 1.0f); }
  }
  if (b == 0 && t == 0) off[N] = E;
  __syncthreads();
  for (int i = t; i < 1024; i += 256) cnt[i] = loff[i];
  __syncthreads();
  for (int i = t; i < cb; i += 256) {
    uint32_t v = bd[i];
    int p = atomicAdd(&cnt[v >> SBITS], 1);
    csr[gb + p] = (int)(v & ((1u << SBITS) - 1));
  }
}

// ---------------- scan machinery ----------------
__global__ void scan1_kernel(const int* __restrict__ cnt, int* __restrict__ off,
                             int* __restrict__ bsum, float* __restrict__ dis, int N) {
  __shared__ int wsum[4];
  int t = threadIdx.x, lane = t & 63, w = t >> 6;
  int base = blockIdx.x * 1024 + t * 4;
  int v0 = (base + 0 < N) ? cnt[base + 0] : 0;
  int v1 = (base + 1 < N) ? cnt[base + 1] : 0;
  int v2 = (base + 2 < N) ? cnt[base + 2] : 0;
  int v3 = (base + 3 < N) ? cnt[base + 3] : 0;
  if (dis) {
    if (base + 0 < N) dis[base + 0] = rsqrtf((float)v0 + 1.0f);
    if (base + 1 < N) dis[base + 1] = rsqrtf((float)v1 + 1.0f);
    if (base + 2 < N) dis[base + 2] = rsqrtf((float)v2 + 1.0f);
    if (base + 3 < N) dis[base + 3] = rsqrtf((float)v3 + 1.0f);
  }
  int ts = v0 + v1 + v2 + v3;
  int sc = ts;
  for (int d = 1; d < 64; d <<= 1) {
    int x = __shfl_up(sc, d, 64);
    if (lane >= d) sc += x;
  }
  if (lane == 63) wsum[w] = sc;
  __syncthreads();
  int wo = 0;
  for (int i = 0; i < w; i++) wo += wsum[i];
  int excl = wo + sc - ts;
  if (base + 0 < N) off[base + 0] = excl;
  if (base + 1 < N) off[base + 1] = excl + v0;
  if (base + 2 < N) off[base + 2] = excl + v0 + v1;
  if (base + 3 < N) off[base + 3] = excl + v0 + v1 + v2;
  if (t == 255) bsum[blockIdx.x] = wo + sc;
}

__global__ void scan2_kernel(int* __restrict__ bsum, int nb) {
  if (threadIdx.x == 0 && blockIdx.x == 0) {
    int run = 0;
    for (int i = 0; i < nb; i++) { int v = bsum[i]; bsum[i] = run; run += v; }
  }
}

__global__ void scan3_kernel(int* __restrict__ off, const int* __restrict__ bsum,
                             int* __restrict__ cur, int N, int E) {
  int i = blockIdx.x * blockDim.x + threadIdx.x;
  if (i < N) {
    int o = off[i] + bsum[i >> 10];
    off[i] = o;
    if (cur) cur[i] = o;
  }
  if (i == 0) off[N] = E;
}

// ---------------- fallback CSR build ----------------
__global__ void hist_part_kernel(const int* __restrict__ dst, int* __restrict__ cnt,
                                 int E, int N) {
  int p = blockIdx.x & (NPART - 1);
  int chunk = blockIdx.x >> 3;
  int lo = (int)((long long)p * N / NPART);
  int hi = (int)((long long)(p + 1) * N / NPART);
  int stride = NCHUNK * 256;
  for (int e = chunk * 256 + threadIdx.x; e < E; e += stride) {
    int d = __builtin_nontemporal_load(&dst[e]);
    if (d >= lo && d < hi) atomicAdd(&cnt[d], 1);
  }
}

__global__ void fill_part_kernel(const int* __restrict__ src, const int* __restrict__ dst,
                                 int* __restrict__ cur, int* __restrict__ csr, int E, int N) {
  int p = blockIdx.x & (NPART - 1);
  int chunk = blockIdx.x >> 3;
  int lo = (int)((long long)p * N / NPART);
  int hi = (int)((long long)(p + 1) * N / NPART);
  int stride = NCHUNK * 256;
  for (int e = chunk * 256 + threadIdx.x; e < E; e += stride) {
    int d = __builtin_nontemporal_load(&dst[e]);
    if (d >= lo && d < hi) {
      int s = __builtin_nontemporal_load(&src[e]);
      int pos = atomicAdd(&cur[d], 1);
      csr[pos] = s;
    }
  }
}

// ---------------- layer 0 aggregation ----------------
__global__ void l0_agg_kernel(const float4* __restrict__ h0s, const float* __restrict__ dis,
                              const int* __restrict__ off, const int* __restrict__ csr,
                              float* __restrict__ cvec, int N) {
  int n = blockIdx.x * blockDim.x + threadIdx.x;
  if (n >= N) return;
  float4 a = h0s[n];
  int e0 = off[n], e1 = off[n + 1];
  int i = e0;
  for (; i + 4 <= e1; i += 4) {
    int s0 = csr[i], s1 = csr[i + 1], s2 = csr[i + 2], s3 = csr[i + 3];
    float4 v0 = h0s[s0], v1 = h0s[s1], v2 = h0s[s2], v3 = h0s[s3];
    a.x += v0.x + v1.x + v2.x + v3.x;
    a.y += v0.y + v1.y + v2.y + v3.y;
    a.z += v0.z + v1.z + v2.z + v3.z;
    a.w += v0.w + v1.w + v2.w + v3.w;
  }
  for (; i < e1; i++) {
    float4 v = h0s[csr[i]];
    a.x += v.x; a.y += v.y; a.z += v.z; a.w += v.w;
  }
  float dn = dis[n];
  float* cv = cvec + (size_t)n * 8;
  cv[0] = dn * a.x; cv[1] = dn * a.y; cv[2] = dn * a.z; cv[3] = dn * a.w;
}

__global__ void l0_combine_kernel(const float* __restrict__ cvec, const float* __restrict__ W0,
                                  const float* __restrict__ b0, const float* __restrict__ resW,
                                  const float* __restrict__ resb, const float* __restrict__ dis,
                                  float* __restrict__ h1, __hip_bfloat16* __restrict__ hbout) {
  int idx = blockIdx.x * blockDim.x + threadIdx.x;
  int n = idx >> 7, c = idx & 127;
  const float* cv = cvec + (size_t)n * 8;
  float acc = b0[c] + resb[c];
#pragma unroll
  for (int k = 0; k < 4; k++) {
    acc += cv[k] * W0[k * HID + c];
    acc += cv[4 + k] * resW[k * HID + c];
  }
  float v = fmaxf(acc, 0.0f);
  h1[idx] = v;
  if (hbout) hbout[idx] = __float2bfloat16(dis[n] * v);
}

// ---------------- 128-dim aggregation, bf16 pre-scaled gather ----------------
__global__ void agg_hid_bf16_kernel(const uint32_t* __restrict__ hb, const float* __restrict__ dis,
                                    const int* __restrict__ off, const int* __restrict__ csr,
                                    float* __restrict__ out, int N) {
  int node = blockIdx.x * 4 + (threadIdx.x >> 6);
  int lane = threadIdx.x & 63;
  if (node >= N) return;
  uint32_t w = hb[(size_t)node * 64 + lane];
  float a0 = __uint_as_float(w << 16);
  float a1 = __uint_as_float(w & 0xffff0000u);
  int e0 = off[node], e1 = off[node + 1];
  int i = e0;
  for (; i + 4 <= e1; i += 4) {
    int s0 = csr[i], s1 = csr[i + 1], s2 = csr[i + 2], s3 = csr[i + 3];
    uint32_t w0 = hb[(size_t)s0 * 64 + lane];
    uint32_t w1 = hb[(size_t)s1 * 64 + lane];
    uint32_t w2 = hb[(size_t)s2 * 64 + lane];
    uint32_t w3 = hb[(size_t)s3 * 64 + lane];
    a0 += __uint_as_float(w0 << 16);  a1 += __uint_as_float(w0 & 0xffff0000u);
    a0 += __uint_as_float(w1 << 16);  a1 += __uint_as_float(w1 & 0xffff0000u);
    a0 += __uint_as_float(w2 << 16);  a1 += __uint_as_float(w2 & 0xffff0000u);
    a0 += __uint_as_float(w3 << 16);  a1 += __uint_as_float(w3 & 0xffff0000u);
  }
  for (; i < e1; i++) {
    uint32_t ww = hb[(size_t)csr[i] * 64 + lane];
    a0 += __uint_as_float(ww << 16);
    a1 += __uint_as_float(ww & 0xffff0000u);
  }
  float dn = dis[node];
  *(float2*)&out[(size_t)node * HID + 2 * lane] = make_float2(dn * a0, dn * a1);
}

__global__ void agg_hid_kernel(const float* __restrict__ h, const float* __restrict__ dis,
                               const int* __restrict__ off, const int* __restrict__ csr,
                               float* __restrict__ out, int N) {
  int node = blockIdx.x * 4 + (threadIdx.x >> 6);
  int lane = threadIdx.x & 63;
  if (node >= N) return;
  float dn = dis[node];
  const float* hrow = h + (size_t)node * HID;
  float a0 = dn * hrow[lane];
  float a1 = dn * hrow[lane + 64];
  int e0 = off[node], e1 = off[node + 1];
  for (int i = e0; i < e1; i++) {
    int s = csr[i];
    float d = dis[s];
    const float* hs = h + (size_t)s * HID;
    a0 += d * hs[lane];
    a1 += d * hs[lane + 64];
  }
  out[(size_t)node * HID + lane] = dn * a0;
  out[(size_t)node * HID + lane + 64] = dn * a1;
}

// ---------------- h_next = relu(agg @ W + b + h_res) ----------------
__global__ void gemm_resid_relu_kernel(float* __restrict__ ag, const float* __restrict__ hres,
                                       const float* __restrict__ W, const float* __restrict__ b,
                                       const float* __restrict__ dis,
                                       __hip_bfloat16* __restrict__ hbout, int N) {
  __shared__ float ash[64 * HID];
  int t = threadIdx.x;
  int n0 = blockIdx.x * 64;
  for (int i = t; i < 64 * HID; i += 256) {
    int gn = n0 + (i >> 7);
    ash[i] = (gn < N) ? ag[(size_t)gn * HID + (i & 127)] : 0.0f;
  }
  __syncthreads();
  int tc = t & 31;
  int tn = t >> 5;
  float acc[8][4];
#pragma unroll
  for (int j = 0; j < 8; j++)
#pragma unroll
    for (int q = 0; q < 4; q++) acc[j][q] = 0.0f;

  for (int k = 0; k < HID; k += 4) {
    float4 w0 = *(const float4*)&W[(k + 0) * HID + tc * 4];
    float4 w1 = *(const float4*)&W[(k + 1) * HID + tc * 4];
    float4 w2 = *(const float4*)&W[(k + 2) * HID + tc * 4];
    float4 w3 = *(const float4*)&W[(k + 3) * HID + tc * 4];
#pragma unroll
    for (int j = 0; j < 8; j++) {
      float4 a = *(const float4*)&ash[(tn * 8 + j) * HID + k];
      acc[j][0] += a.x * w0.x + a.y * w1.x + a.z * w2.x + a.w * w3.x;
      acc[j][1] += a.x * w0.y + a.y * w1.y + a.z * w2.y + a.w * w3.y;
      acc[j][2] += a.x * w0.z + a.y * w1.z + a.z * w2.z + a.w * w3.z;
      acc[j][3] += a.x * w0.w + a.y * w1.w + a.z * w2.w + a.w * w3.w;
    }
  }
  float4 bv = *(const float4*)&b[tc * 4];
#pragma unroll
  for (int j = 0; j < 8; j++) {
    int gn = n0 + tn * 8 + j;
    if (gn < N) {
      float4 hv = *(const float4*)&hres[(size_t)gn * HID + tc * 4];
      float4 o;
      o.x = fmaxf(acc[j][0] + bv.x + hv.x, 0.0f);
      o.y = fmaxf(acc[j][1] + bv.y + hv.y, 0.0f);
      o.z = fmaxf(acc[j][2] + bv.z + hv.z, 0.0f);
      o.w = fmaxf(acc[j][3] + bv.w + hv.w, 0.0f);
      *(float4*)&ag[(size_t)gn * HID + tc * 4] = o;
      if (hbout) {
        float dnn = dis[gn];
        __hip_bfloat162 p01 = __float22bfloat162_rn(make_float2(dnn * o.x, dnn * o.y));
        __hip_bfloat162 p23 = __float22bfloat162_rn(make_float2(dnn * o.z, dnn * o.w));
        *(__hip_bfloat162*)&hbout[(size_t)gn * HID + tc * 4] = p01;
        *(__hip_bfloat162*)&hbout[(size_t)gn * HID + tc * 4 + 2] = p23;
      }
    }
  }
}

// ---------------- final fc ----------------
__global__ void fc_kernel(const float* __restrict__ h3, const float* __restrict__ fcW,
                          const float* __restrict__ fcb, float* __restrict__ out, int N) {
  __shared__ float sh[64 * 130];
  int t = threadIdx.x;
  int n0 = blockIdx.x * 64;
  for (int i = t; i < 64 * HID; i += 256) {
    int n = i >> 7, k = i & 127;
    int gn = n0 + n;
    sh[n * 130 + k] = (gn < N) ? h3[(size_t)gn * HID + k] : 0.0f;
  }
  __syncthreads();
  int nl = t >> 2, j = t & 3;
  float acc = fcb[j];
  for (int k = 0; k < HID; k++) acc += sh[nl * 130 + k] * fcW[k * 4 + j];
  int gn = n0 + nl;
  if (gn < N) out[(size_t)gn * 4 + j] = acc;
}

// ---------------- host ----------------
extern "C" void kernel_launch(void* const* d_in, const int* in_sizes, int n_in,
                              void* d_out, int out_size, void* d_ws, size_t ws_size,
                              hipStream_t stream) {
  const float* x = (const float*)d_in[0];
  const int* edge = (const int*)d_in[1];
  const void* maskp = d_in[2];
  const float* W0 = (const float*)d_in[3];
  const float* b0 = (const float*)d_in[4];
  const float* resW = (const float*)d_in[5];
  const float* resb = (const float*)d_in[6];
  const float* W1 = (const float*)d_in[7];
  const float* b1 = (const float*)d_in[8];
  const float* W2 = (const float*)d_in[9];
  const float* b2 = (const float*)d_in[10];
  const float* fcW = (const float*)d_in[11];
  const float* fcb = (const float*)d_in[12];
  float* out = (float*)d_out;

  int N = in_sizes[0] / 4;
  int E = in_sizes[1] / 2;
  const int* srcp = edge;
  const int* dstp = edge + E;

  char* ws = (char*)d_ws;
  size_t cursor = 0;
  auto alloc = [&](size_t bytes) { char* p = ws + cursor; cursor += (bytes + 511) & ~(size_t)511; return p; };
  int* flags = (int*)alloc(16);
  int* cnt = (int*)alloc((size_t)N * 4);   // fallback path only
  float* dis = (float*)alloc((size_t)N * 4);
  int* off = (int*)alloc((size_t)(N + 1) * 4);
  int* bsum = (int*)alloc(1024);
  int nbin = (N + 1023) >> 10;
  int* gcur = (int*)alloc((size_t)(nbin + 1) * 4);
  int* btot = (int*)alloc((size_t)(nbin + 1) * 4);
  int* bstart = (int*)alloc((size_t)(nbin + 1) * 4);
  int* csr = (int*)alloc((size_t)E * 4);
  float* h0s = (float*)alloc((size_t)N * 4 * 4);
  float* cvec = (float*)alloc((size_t)N * 8 * 4);
  float* buf0 = (float*)alloc((size_t)N * HID * 4);
  float* buf1 = (float*)alloc((size_t)N * HID * 4);
  size_t base_cursor = cursor;
  __hip_bfloat16* hb = (__hip_bfloat16*)alloc((size_t)N * HID * 2);
  bool use_bf16 = (cursor <= ws_size);
  if (!use_bf16) {
    hb = nullptr;
    if (base_cursor > ws_size) return;
  }

  // radix staging capacity per bucket: 1.25x expected + slack, multiple of 64
  long long expect = (long long)E / (nbin > 0 ? nbin : 1);
  int CAPB = (int)((((expect * 5) / 4 + 127) / 64) * 64);
  if (CAPB < 256) CAPB = 256;
  size_t bdata_bytes = (size_t)nbin * CAPB * 4;
  bool use_radix = (N <= (1 << SBITS)) && (nbin <= 1024) &&
                   (bdata_bytes <= (size_t)N * HID * 4);
  uint32_t* bdata = (uint32_t*)buf1;  // staging aliases buf1 (dead until layer-1 agg)

  int nThreadsN = (N + 255) / 256;

  hipMemsetAsync(flags, 0, 16, stream);
  detect_mask_kernel<<<256, 256, 0, stream>>>((const unsigned char*)maskp, N, N / 4, flags);

  if (use_radix) {
    init_gcur_kernel<<<(nbin + 255) / 256, 256, 0, stream>>>(gcur, nbin, CAPB);
    radixA_kernel<<<(E + MCHUNK - 1) / MCHUNK, 256, 0, stream>>>(srcp, dstp, gcur, bdata,
                                                                 nbin, CAPB, E);
    btotB_kernel<<<(nbin + 255) / 256, 256, 0, stream>>>(gcur, btot, nbin, CAPB);
    scan1_kernel<<<1, 256, 0, stream>>>(btot, bstart, bsum, nullptr, nbin);
    scan2_kernel<<<1, 64, 0, stream>>>(bsum, 1);
    scan3_kernel<<<(nbin + 255) / 256, 256, 0, stream>>>(bstart, bsum, nullptr, nbin, E);
    radixB_kernel<<<nbin, 256, 0, stream>>>(bdata, gcur, bstart, CAPB, off, dis, csr, N, E);
  } else {
    hipMemsetAsync(cnt, 0, (size_t)N * 4, stream);
    int nb = (N + 1023) / 1024;
    hist_part_kernel<<<NPART * NCHUNK, 256, 0, stream>>>(dstp, cnt, E, N);
    scan1_kernel<<<nb, 256, 0, stream>>>(cnt, off, bsum, dis, N);
    scan2_kernel<<<1, 64, 0, stream>>>(bsum, nb);
    scan3_kernel<<<nThreadsN, 256, 0, stream>>>(off, bsum, cnt, N, E);
    fill_part_kernel<<<NPART * NCHUNK, 256, 0, stream>>>(srcp, dstp, cnt, csr, E, N);
  }

  expand_mask_h0<<<nThreadsN, 256, 0, stream>>>(maskp, (const float4*)x, flags, dis,
                                                out + (size_t)N * 4, cvec, (float4*)h0s, N);

  // layer 0
  l0_agg_kernel<<<nThreadsN, 256, 0, stream>>>((const float4*)h0s, dis, off, csr, cvec, N);
  l0_combine_kernel<<<(N * HID + 255) / 256, 256, 0, stream>>>(cvec, W0, b0, resW, resb, dis,
                                                               buf0, hb);

  // layer 1: agg(h1) -> buf1 ; h2 = relu(buf1@W1 + b1 + buf0) -> buf1 (+ hb)
  if (use_bf16)
    agg_hid_bf16_kernel<<<(N + 3) / 4, 256, 0, stream>>>((const uint32_t*)hb, dis, off, csr, buf1, N);
  else
    agg_hid_kernel<<<(N + 3) / 4, 256, 0, stream>>>(buf0, dis, off, csr, buf1, N);
  gemm_resid_relu_kernel<<<(N + 63) / 64, 256, 0, stream>>>(buf1, buf0, W1, b1, dis, hb, N);

  // layer 2: agg(h2) -> buf0 ; h3 = relu(buf0@W2 + b2 + buf1) -> buf0
  if (use_bf16)
    agg_hid_bf16_kernel<<<(N + 3) / 4, 256, 0, stream>>>((const uint32_t*)hb, dis, off, csr, buf0, N);
  else
    agg_hid_kernel<<<(N + 3) / 4, 256, 0, stream>>>(buf1, dis, off, csr, buf0, N);
  gemm_resid_relu_kernel<<<(N + 63) / 64, 256, 0, stream>>>(buf0, buf1, W2, b2, dis, nullptr, N);

  // output
  fc_kernel<<<(N + 63) / 64, 256, 0, stream>>>(buf0, fcW, fcb, out, N);
}

// Round 8
// 555.617 us; speedup vs baseline: 1.4202x; 1.0912x over previous
//
#include <hip/hip_runtime.h>
#include <hip/hip_bf16.h>
#include <stdint.h>

#define HID 128
#define NPART 8
#define NCHUNK 256
#define MCHUNK 4096   // edges per radixA block
#define LBITS 10      // local dst bits; bucket = dst>>LBITS
#define SBITS 22      // src bits in packed word (N must be <= 1<<22)

// ---------------- mask storage detection ----------------
__global__ void detect_mask_kernel(const unsigned char* __restrict__ p, int nbytes,
                                   int nfloat, int* __restrict__ flags) {
  int stride = blockDim.x * gridDim.x;
  for (int i = blockIdx.x * blockDim.x + threadIdx.x; i < nbytes; i += stride) {
    if ((i & 3) && p[i] != 0) { atomicOr(&flags[0], 1); break; }
  }
  const float* fp = (const float*)p;
  for (int i = blockIdx.x * blockDim.x + threadIdx.x; i < nfloat; i += stride) {
    float f = fp[i];
    if (!(f == 0.0f || f == 1.0f)) { atomicOr(&flags[1], 1); break; }
  }
}

__global__ void expand_mask_h0(const void* __restrict__ maskp, const float4* __restrict__ x4,
                               const int* __restrict__ flags, const float* __restrict__ dis,
                               float* __restrict__ maskout, float* __restrict__ cvec,
                               float4* __restrict__ h0s, int N) {
  int i = blockIdx.x * blockDim.x + threadIdx.x;
  if (i >= N) return;
  float m;
  if (flags[0] == 0)      m = (((const int*)maskp)[i] != 0) ? 1.f : 0.f;
  else if (flags[1] == 0) m = (((const float*)maskp)[i] != 0.f) ? 1.f : 0.f;
  else                    m = (((const unsigned char*)maskp)[i] != 0) ? 1.f : 0.f;
  maskout[i] = m;
  float4 xv = x4[i];
  float4 h0 = make_float4(m * xv.x, m * xv.y, m * xv.z, m * xv.w);
  float* cv = cvec + (size_t)i * 8;
  cv[4] = h0.x; cv[5] = h0.y; cv[6] = h0.z; cv[7] = h0.w;
  float d = dis[i];
  h0s[i] = make_float4(d * h0.x, d * h0.y, d * h0.z, d * h0.w);
}

// ---------------- CSR build: two-pass LDS-staged radix ----------------
__global__ void init_gcur_kernel(int* __restrict__ gcur, int n, int CAPB) {
  int i = blockIdx.x * blockDim.x + threadIdx.x;
  if (i < n) gcur[i] = i * CAPB;
}

__global__ void radixA_kernel(const int* __restrict__ src, const int* __restrict__ dst,
                              int* __restrict__ gcur, uint32_t* __restrict__ bdata,
                              int nbin, int CAPB, int E) {
  __shared__ uint32_t sv[MCHUNK];
  __shared__ uint16_t sb[MCHUNK];
  __shared__ int bcnt[1024], boff[1024], gbase[1024];
  __shared__ int wsum[4];
  int t = threadIdx.x;
  int base = blockIdx.x * MCHUNK;
  int m = E - base; if (m > MCHUNK) m = MCHUNK;
  for (int i = t; i < 1024; i += 256) bcnt[i] = 0;
  __syncthreads();
  uint32_t pk[16]; short bn[16];
#pragma unroll
  for (int j = 0; j < 16; j++) {
    int i = base + t + j * 256;
    if (i < base + m) {
      int d = __builtin_nontemporal_load(&dst[i]);
      int s = __builtin_nontemporal_load(&src[i]);
      int b = d >> LBITS;
      pk[j] = ((uint32_t)(d & ((1 << LBITS) - 1)) << SBITS) | (uint32_t)s;
      bn[j] = (short)b;
      atomicAdd(&bcnt[b], 1);
    } else bn[j] = -1;
  }
  __syncthreads();
  {
    int lane = t & 63, w = t >> 6, i0 = t * 4;
    int v0 = bcnt[i0], v1 = bcnt[i0 + 1], v2 = bcnt[i0 + 2], v3 = bcnt[i0 + 3];
    int ts = v0 + v1 + v2 + v3, sc = ts;
    for (int d = 1; d < 64; d <<= 1) { int x = __shfl_up(sc, d, 64); if (lane >= d) sc += x; }
    if (lane == 63) wsum[w] = sc;
    __syncthreads();
    int wo = 0;
    for (int k = 0; k < w; k++) wo += wsum[k];
    int excl = wo + sc - ts;
    boff[i0] = excl; boff[i0 + 1] = excl + v0;
    boff[i0 + 2] = excl + v0 + v1; boff[i0 + 3] = excl + v0 + v1 + v2;
  }
  __syncthreads();
  for (int i = t; i < nbin; i += 256) {
    int c = bcnt[i];
    gbase[i] = c ? atomicAdd(&gcur[i], c) : 0;
  }
  __syncthreads();
  for (int i = t; i < nbin; i += 256) bcnt[i] = boff[i];
  __syncthreads();
#pragma unroll
  for (int j = 0; j < 16; j++) {
    if (bn[j] >= 0) {
      int p = atomicAdd(&bcnt[bn[j]], 1);
      sv[p] = pk[j];
      sb[p] = (uint16_t)bn[j];
    }
  }
  __syncthreads();
  for (int i = t; i < m; i += 256) {
    int b = sb[i];
    int gp = gbase[b] + (i - boff[b]);
    if (gp < (b + 1) * CAPB) bdata[gp] = sv[i];
  }
}

// fused btot + scan (single block, nbin <= 1024)
__global__ void bucket_meta_kernel(const int* __restrict__ gcur, int* __restrict__ bstart,
                                   int nbin, int CAPB) {
  __shared__ int wsum[4];
  int t = threadIdx.x, lane = t & 63, w = t >> 6, i0 = t * 4;
  int v[4];
#pragma unroll
  for (int q = 0; q < 4; q++) {
    int i = i0 + q;
    int c = 0;
    if (i < nbin) {
      c = gcur[i] - i * CAPB;
      if (c > CAPB) c = CAPB;
    }
    v[q] = c;
  }
  int ts = v[0] + v[1] + v[2] + v[3], sc = ts;
  for (int d = 1; d < 64; d <<= 1) { int x = __shfl_up(sc, d, 64); if (lane >= d) sc += x; }
  if (lane == 63) wsum[w] = sc;
  __syncthreads();
  int wo = 0;
  for (int k = 0; k < w; k++) wo += wsum[k];
  int excl = wo + sc - ts;
  int e[4] = {excl, excl + v[0], excl + v[0] + v[1], excl + v[0] + v[1] + v[2]};
#pragma unroll
  for (int q = 0; q < 4; q++)
    if (i0 + q < nbin) bstart[i0 + q] = e[q];
  if (t == 255) bstart[nbin] = wo + sc;
}

__global__ void radixB_kernel(const uint32_t* __restrict__ bdata, const int* __restrict__ gcur,
                              const int* __restrict__ bstart, int CAPB,
                              int* __restrict__ off, float* __restrict__ dis,
                              int* __restrict__ csr, int N, int E) {
  __shared__ int cnt[1024], loff[1024];
  __shared__ int wsum[4];
  int b = blockIdx.x, t = threadIdx.x;
  int cb = gcur[b] - b * CAPB; if (cb > CAPB) cb = CAPB;
  int gb = bstart[b];
  const uint32_t* bd = bdata + (size_t)b * CAPB;
  for (int i = t; i < 1024; i += 256) cnt[i] = 0;
  __syncthreads();
  for (int i = t; i < cb; i += 256) atomicAdd(&cnt[bd[i] >> SBITS], 1);
  __syncthreads();
  {
    int lane = t & 63, w = t >> 6, i0 = t * 4;
    int v0 = cnt[i0], v1 = cnt[i0 + 1], v2 = cnt[i0 + 2], v3 = cnt[i0 + 3];
    int ts = v0 + v1 + v2 + v3, sc = ts;
    for (int d = 1; d < 64; d <<= 1) { int x = __shfl_up(sc, d, 64); if (lane >= d) sc += x; }
    if (lane == 63) wsum[w] = sc;
    __syncthreads();
    int wo = 0;
    for (int k = 0; k < w; k++) wo += wsum[k];
    int e0 = wo + sc - ts;
    int e1 = e0 + v0, e2 = e1 + v1, e3 = e2 + v2;
    loff[i0] = e0; loff[i0 + 1] = e1; loff[i0 + 2] = e2; loff[i0 + 3] = e3;
    int d0 = b * 1024 + i0;
    if (d0 + 0 < N) { off[d0 + 0] = gb + e0; dis[d0 + 0] = rsqrtf((float)v0 + 1.0f); }
    if (d0 + 1 < N) { off[d0 + 1] = gb + e1; dis[d0 + 1] = rsqrtf((float)v1 + 1.0f); }
    if (d0 + 2 < N) { off[d0 + 2] = gb + e2; dis[d0 + 2] = rsqrtf((float)v2 + 1.0f); }
    if (d0 + 3 < N) { off[d0 + 3] = gb + e3; dis[d0 + 3] = rsqrtf((float)v3 + 1.0f); }
  }
  if (b == 0 && t == 0) off[N] = E;
  __syncthreads();
  for (int i = t; i < 1024; i += 256) cnt[i] = loff[i];
  __syncthreads();
  for (int i = t; i < cb; i += 256) {
    uint32_t v = bd[i];
    int p = atomicAdd(&cnt[v >> SBITS], 1);
    csr[gb + p] = (int)(v & ((1u << SBITS) - 1));
  }
}

// ---------------- scan machinery (fallback path) ----------------
__global__ void scan1_kernel(const int* __restrict__ cnt, int* __restrict__ off,
                             int* __restrict__ bsum, float* __restrict__ dis, int N) {
  __shared__ int wsum[4];
  int t = threadIdx.x, lane = t & 63, w = t >> 6;
  int base = blockIdx.x * 1024 + t * 4;
  int v0 = (base + 0 < N) ? cnt[base + 0] : 0;
  int v1 = (base + 1 < N) ? cnt[base + 1] : 0;
  int v2 = (base + 2 < N) ? cnt[base + 2] : 0;
  int v3 = (base + 3 < N) ? cnt[base + 3] : 0;
  if (dis) {
    if (base + 0 < N) dis[base + 0] = rsqrtf((float)v0 + 1.0f);
    if (base + 1 < N) dis[base + 1] = rsqrtf((float)v1 + 1.0f);
    if (base + 2 < N) dis[base + 2] = rsqrtf((float)v2 + 1.0f);
    if (base + 3 < N) dis[base + 3] = rsqrtf((float)v3 + 1.0f);
  }
  int ts = v0 + v1 + v2 + v3;
  int sc = ts;
  for (int d = 1; d < 64; d <<= 1) {
    int x = __shfl_up(sc, d, 64);
    if (lane >= d) sc += x;
  }
  if (lane == 63) wsum[w] = sc;
  __syncthreads();
  int wo = 0;
  for (int i = 0; i < w; i++) wo += wsum[i];
  int excl = wo + sc - ts;
  if (base + 0 < N) off[base + 0] = excl;
  if (base + 1 < N) off[base + 1] = excl + v0;
  if (base + 2 < N) off[base + 2] = excl + v0 + v1;
  if (base + 3 < N) off[base + 3] = excl + v0 + v1 + v2;
  if (t == 255) bsum[blockIdx.x] = wo + sc;
}

__global__ void scan2_kernel(int* __restrict__ bsum, int nb) {
  if (threadIdx.x == 0 && blockIdx.x == 0) {
    int run = 0;
    for (int i = 0; i < nb; i++) { int v = bsum[i]; bsum[i] = run; run += v; }
  }
}

__global__ void scan3_kernel(int* __restrict__ off, const int* __restrict__ bsum,
                             int* __restrict__ cur, int N, int E) {
  int i = blockIdx.x * blockDim.x + threadIdx.x;
  if (i < N) {
    int o = off[i] + bsum[i >> 10];
    off[i] = o;
    if (cur) cur[i] = o;
  }
  if (i == 0) off[N] = E;
}

__global__ void hist_part_kernel(const int* __restrict__ dst, int* __restrict__ cnt,
                                 int E, int N) {
  int p = blockIdx.x & (NPART - 1);
  int chunk = blockIdx.x >> 3;
  int lo = (int)((long long)p * N / NPART);
  int hi = (int)((long long)(p + 1) * N / NPART);
  int stride = NCHUNK * 256;
  for (int e = chunk * 256 + threadIdx.x; e < E; e += stride) {
    int d = __builtin_nontemporal_load(&dst[e]);
    if (d >= lo && d < hi) atomicAdd(&cnt[d], 1);
  }
}

__global__ void fill_part_kernel(const int* __restrict__ src, const int* __restrict__ dst,
                                 int* __restrict__ cur, int* __restrict__ csr, int E, int N) {
  int p = blockIdx.x & (NPART - 1);
  int chunk = blockIdx.x >> 3;
  int lo = (int)((long long)p * N / NPART);
  int hi = (int)((long long)(p + 1) * N / NPART);
  int stride = NCHUNK * 256;
  for (int e = chunk * 256 + threadIdx.x; e < E; e += stride) {
    int d = __builtin_nontemporal_load(&dst[e]);
    if (d >= lo && d < hi) {
      int s = __builtin_nontemporal_load(&src[e]);
      int pos = atomicAdd(&cur[d], 1);
      csr[pos] = s;
    }
  }
}

// ---------------- layer 0 aggregation ----------------
__global__ void l0_agg_kernel(const float4* __restrict__ h0s, const float* __restrict__ dis,
                              const int* __restrict__ off, const int* __restrict__ csr,
                              float* __restrict__ cvec, int N) {
  int n = blockIdx.x * blockDim.x + threadIdx.x;
  if (n >= N) return;
  float4 a = h0s[n];
  int e0 = off[n], e1 = off[n + 1];
  int i = e0;
  for (; i + 4 <= e1; i += 4) {
    int s0 = csr[i], s1 = csr[i + 1], s2 = csr[i + 2], s3 = csr[i + 3];
    float4 v0 = h0s[s0], v1 = h0s[s1], v2 = h0s[s2], v3 = h0s[s3];
    a.x += v0.x + v1.x + v2.x + v3.x;
    a.y += v0.y + v1.y + v2.y + v3.y;
    a.z += v0.z + v1.z + v2.z + v3.z;
    a.w += v0.w + v1.w + v2.w + v3.w;
  }
  for (; i < e1; i++) {
    float4 v = h0s[csr[i]];
    a.x += v.x; a.y += v.y; a.z += v.z; a.w += v.w;
  }
  float dn = dis[n];
  float* cv = cvec + (size_t)n * 8;
  cv[0] = dn * a.x; cv[1] = dn * a.y; cv[2] = dn * a.z; cv[3] = dn * a.w;
}

__global__ void l0_combine_kernel(const float* __restrict__ cvec, const float* __restrict__ W0,
                                  const float* __restrict__ b0, const float* __restrict__ resW,
                                  const float* __restrict__ resb, const float* __restrict__ dis,
                                  float* __restrict__ h1, __hip_bfloat16* __restrict__ hbout) {
  int idx = blockIdx.x * blockDim.x + threadIdx.x;
  int n = idx >> 7, c = idx & 127;
  const float* cv = cvec + (size_t)n * 8;
  float acc = b0[c] + resb[c];
#pragma unroll
  for (int k = 0; k < 4; k++) {
    acc += cv[k] * W0[k * HID + c];
    acc += cv[4 + k] * resW[k * HID + c];
  }
  float v = fmaxf(acc, 0.0f);
  h1[idx] = v;
  if (hbout) hbout[idx] = __float2bfloat16(dis[n] * v);
}

// ---------------- 128-dim aggregation, bf16 pre-scaled gather, unroll 8 ----------------
#define ACC1(W) { a0 += __uint_as_float((W) << 16); a1 += __uint_as_float((W) & 0xffff0000u); }
__global__ void agg_hid_bf16_kernel(const uint32_t* __restrict__ hb, const float* __restrict__ dis,
                                    const int* __restrict__ off, const int* __restrict__ csr,
                                    float* __restrict__ out, int N) {
  int node = blockIdx.x * 4 + (threadIdx.x >> 6);
  int lane = threadIdx.x & 63;
  if (node >= N) return;
  uint32_t w = hb[(size_t)node * 64 + lane];
  float a0 = __uint_as_float(w << 16);
  float a1 = __uint_as_float(w & 0xffff0000u);
  int e0 = off[node], e1 = off[node + 1];
  int i = e0;
  for (; i + 8 <= e1; i += 8) {
    int s0 = csr[i],     s1 = csr[i + 1], s2 = csr[i + 2], s3 = csr[i + 3];
    int s4 = csr[i + 4], s5 = csr[i + 5], s6 = csr[i + 6], s7 = csr[i + 7];
    uint32_t w0 = hb[(size_t)s0 * 64 + lane];
    uint32_t w1 = hb[(size_t)s1 * 64 + lane];
    uint32_t w2 = hb[(size_t)s2 * 64 + lane];
    uint32_t w3 = hb[(size_t)s3 * 64 + lane];
    uint32_t w4 = hb[(size_t)s4 * 64 + lane];
    uint32_t w5 = hb[(size_t)s5 * 64 + lane];
    uint32_t w6 = hb[(size_t)s6 * 64 + lane];
    uint32_t w7 = hb[(size_t)s7 * 64 + lane];
    ACC1(w0) ACC1(w1) ACC1(w2) ACC1(w3) ACC1(w4) ACC1(w5) ACC1(w6) ACC1(w7)
  }
  for (; i + 4 <= e1; i += 4) {
    int s0 = csr[i], s1 = csr[i + 1], s2 = csr[i + 2], s3 = csr[i + 3];
    uint32_t w0 = hb[(size_t)s0 * 64 + lane];
    uint32_t w1 = hb[(size_t)s1 * 64 + lane];
    uint32_t w2 = hb[(size_t)s2 * 64 + lane];
    uint32_t w3 = hb[(size_t)s3 * 64 + lane];
    ACC1(w0) ACC1(w1) ACC1(w2) ACC1(w3)
  }
  for (; i < e1; i++) {
    uint32_t ww = hb[(size_t)csr[i] * 64 + lane];
    ACC1(ww)
  }
  float dn = dis[node];
  *(float2*)&out[(size_t)node * HID + 2 * lane] = make_float2(dn * a0, dn * a1);
}

__global__ void agg_hid_kernel(const float* __restrict__ h, const float* __restrict__ dis,
                               const int* __restrict__ off, const int* __restrict__ csr,
                               float* __restrict__ out, int N) {
  int node = blockIdx.x * 4 + (threadIdx.x >> 6);
  int lane = threadIdx.x & 63;
  if (node >= N) return;
  float dn = dis[node];
  const float* hrow = h + (size_t)node * HID;
  float a0 = dn * hrow[lane];
  float a1 = dn * hrow[lane + 64];
  int e0 = off[node], e1 = off[node + 1];
  for (int i = e0; i < e1; i++) {
    int s = csr[i];
    float d = dis[s];
    const float* hs = h + (size_t)s * HID;
    a0 += d * hs[lane];
    a1 += d * hs[lane + 64];
  }
  out[(size_t)node * HID + lane] = dn * a0;
  out[(size_t)node * HID + lane + 64] = dn * a1;
}

// ---------------- h_next = relu(agg @ W + b + h_res), in-place, + bf16 emit ----------------
__global__ void gemm_resid_relu_kernel(float* __restrict__ ag, const float* __restrict__ hres,
                                       const float* __restrict__ W, const float* __restrict__ b,
                                       const float* __restrict__ dis,
                                       __hip_bfloat16* __restrict__ hbout, int N) {
  __shared__ float ash[64 * HID];
  int t = threadIdx.x;
  int n0 = blockIdx.x * 64;
  for (int i = t; i < 64 * HID; i += 256) {
    int gn = n0 + (i >> 7);
    ash[i] = (gn < N) ? ag[(size_t)gn * HID + (i & 127)] : 0.0f;
  }
  __syncthreads();
  int tc = t & 31;
  int tn = t >> 5;
  float acc[8][4];
#pragma unroll
  for (int j = 0; j < 8; j++)
#pragma unroll
    for (int q = 0; q < 4; q++) acc[j][q] = 0.0f;

  for (int k = 0; k < HID; k += 4) {
    float4 w0 = *(const float4*)&W[(k + 0) * HID + tc * 4];
    float4 w1 = *(const float4*)&W[(k + 1) * HID + tc * 4];
    float4 w2 = *(const float4*)&W[(k + 2) * HID + tc * 4];
    float4 w3 = *(const float4*)&W[(k + 3) * HID + tc * 4];
#pragma unroll
    for (int j = 0; j < 8; j++) {
      float4 a = *(const float4*)&ash[(tn * 8 + j) * HID + k];
      acc[j][0] += a.x * w0.x + a.y * w1.x + a.z * w2.x + a.w * w3.x;
      acc[j][1] += a.x * w0.y + a.y * w1.y + a.z * w2.y + a.w * w3.y;
      acc[j][2] += a.x * w0.z + a.y * w1.z + a.z * w2.z + a.w * w3.z;
      acc[j][3] += a.x * w0.w + a.y * w1.w + a.z * w2.w + a.w * w3.w;
    }
  }
  float4 bv = *(const float4*)&b[tc * 4];
#pragma unroll
  for (int j = 0; j < 8; j++) {
    int gn = n0 + tn * 8 + j;
    if (gn < N) {
      float4 hv = *(const float4*)&hres[(size_t)gn * HID + tc * 4];
      float4 o;
      o.x = fmaxf(acc[j][0] + bv.x + hv.x, 0.0f);
      o.y = fmaxf(acc[j][1] + bv.y + hv.y, 0.0f);
      o.z = fmaxf(acc[j][2] + bv.z + hv.z, 0.0f);
      o.w = fmaxf(acc[j][3] + bv.w + hv.w, 0.0f);
      *(float4*)&ag[(size_t)gn * HID + tc * 4] = o;
      if (hbout) {
        float dnn = dis[gn];
        __hip_bfloat162 p01 = __float22bfloat162_rn(make_float2(dnn * o.x, dnn * o.y));
        __hip_bfloat162 p23 = __float22bfloat162_rn(make_float2(dnn * o.z, dnn * o.w));
        *(__hip_bfloat162*)&hbout[(size_t)gn * HID + tc * 4] = p01;
        *(__hip_bfloat162*)&hbout[(size_t)gn * HID + tc * 4 + 2] = p23;
      }
    }
  }
}

// ---------------- layer 2 fused: h3 = relu(agg@W + b + hres); out = h3@fcW + fcb ----------------
// h3 never touches global memory: each node row lives across 32 lanes (4 cols each);
// fc = 16 FMA vs in-register fcW + 5-step half-wave shfl_xor reduction.
__global__ void gemm_resid_fc_kernel(const float* __restrict__ ag, const float* __restrict__ hres,
                                     const float* __restrict__ W, const float* __restrict__ b,
                                     const float* __restrict__ fcW, const float* __restrict__ fcb,
                                     float* __restrict__ out, int N) {
  __shared__ float ash[64 * HID];
  int t = threadIdx.x;
  int n0 = blockIdx.x * 64;
  for (int i = t; i < 64 * HID; i += 256) {
    int gn = n0 + (i >> 7);
    ash[i] = (gn < N) ? ag[(size_t)gn * HID + (i & 127)] : 0.0f;
  }
  __syncthreads();
  int tc = t & 31;
  int tn = t >> 5;
  float acc[8][4];
#pragma unroll
  for (int j = 0; j < 8; j++)
#pragma unroll
    for (int q = 0; q < 4; q++) acc[j][q] = 0.0f;

  for (int k = 0; k < HID; k += 4) {
    float4 w0 = *(const float4*)&W[(k + 0) * HID + tc * 4];
    float4 w1 = *(const float4*)&W[(k + 1) * HID + tc * 4];
    float4 w2 = *(const float4*)&W[(k + 2) * HID + tc * 4];
    float4 w3 = *(const float4*)&W[(k + 3) * HID + tc * 4];
#pragma unroll
    for (int j = 0; j < 8; j++) {
      float4 a = *(const float4*)&ash[(tn * 8 + j) * HID + k];
      acc[j][0] += a.x * w0.x + a.y * w1.x + a.z * w2.x + a.w * w3.x;
      acc[j][1] += a.x * w0.y + a.y * w1.y + a.z * w2.y + a.w * w3.y;
      acc[j][2] += a.x * w0.z + a.y * w1.z + a.z * w2.z + a.w * w3.z;
      acc[j][3] += a.x * w0.w + a.y * w1.w + a.z * w2.w + a.w * w3.w;
    }
  }
  // fcW rows for this thread's 4 columns (each float4 = 4 outputs)
  float4 f0 = *(const float4*)&fcW[(tc * 4 + 0) * 4];
  float4 f1 = *(const float4*)&fcW[(tc * 4 + 1) * 4];
  float4 f2 = *(const float4*)&fcW[(tc * 4 + 2) * 4];
  float4 f3 = *(const float4*)&fcW[(tc * 4 + 3) * 4];
  float4 bv = *(const float4*)&b[tc * 4];
  float4 fb = *(const float4*)&fcb[0];
#pragma unroll
  for (int j = 0; j < 8; j++) {
    int gn = n0 + tn * 8 + j;
    float4 o = make_float4(0.f, 0.f, 0.f, 0.f);
    if (gn < N) {
      float4 hv = *(const float4*)&hres[(size_t)gn * HID + tc * 4];
      o.x = fmaxf(acc[j][0] + bv.x + hv.x, 0.0f);
      o.y = fmaxf(acc[j][1] + bv.y + hv.y, 0.0f);
      o.z = fmaxf(acc[j][2] + bv.z + hv.z, 0.0f);
      o.w = fmaxf(acc[j][3] + bv.w + hv.w, 0.0f);
    }
    float r0 = o.x * f0.x + o.y * f1.x + o.z * f2.x + o.w * f3.x;
    float r1 = o.x * f0.y + o.y * f1.y + o.z * f2.y + o.w * f3.y;
    float r2 = o.x * f0.z + o.y * f1.z + o.z * f2.z + o.w * f3.z;
    float r3 = o.x * f0.w + o.y * f1.w + o.z * f2.w + o.w * f3.w;
#pragma unroll
    for (int d = 1; d < 32; d <<= 1) {
      r0 += __shfl_xor(r0, d, 64);
      r1 += __shfl_xor(r1, d, 64);
      r2 += __shfl_xor(r2, d, 64);
      r3 += __shfl_xor(r3, d, 64);
    }
    if (tc == 0 && gn < N)
      *(float4*)&out[(size_t)gn * 4] =
          make_float4(r0 + fb.x, r1 + fb.y, r2 + fb.z, r3 + fb.w);
  }
}

// ---------------- host ----------------
extern "C" void kernel_launch(void* const* d_in, const int* in_sizes, int n_in,
                              void* d_out, int out_size, void* d_ws, size_t ws_size,
                              hipStream_t stream) {
  const float* x = (const float*)d_in[0];
  const int* edge = (const int*)d_in[1];
  const void* maskp = d_in[2];
  const float* W0 = (const float*)d_in[3];
  const float* b0 = (const float*)d_in[4];
  const float* resW = (const float*)d_in[5];
  const float* resb = (const float*)d_in[6];
  const float* W1 = (const float*)d_in[7];
  const float* b1 = (const float*)d_in[8];
  const float* W2 = (const float*)d_in[9];
  const float* b2 = (const float*)d_in[10];
  const float* fcW = (const float*)d_in[11];
  const float* fcb = (const float*)d_in[12];
  float* out = (float*)d_out;

  int N = in_sizes[0] / 4;
  int E = in_sizes[1] / 2;
  const int* srcp = edge;
  const int* dstp = edge + E;

  char* ws = (char*)d_ws;
  size_t cursor = 0;
  auto alloc = [&](size_t bytes) { char* p = ws + cursor; cursor += (bytes + 511) & ~(size_t)511; return p; };
  int* flags = (int*)alloc(16);
  int* cnt = (int*)alloc((size_t)N * 4);   // fallback path only
  float* dis = (float*)alloc((size_t)N * 4);
  int* off = (int*)alloc((size_t)(N + 1) * 4);
  int* bsum = (int*)alloc(1024);
  int nbin = (N + 1023) >> 10;
  int* gcur = (int*)alloc((size_t)(nbin + 1) * 4);
  int* bstart = (int*)alloc((size_t)(nbin + 1) * 4);
  int* csr = (int*)alloc((size_t)E * 4);
  float* h0s = (float*)alloc((size_t)N * 4 * 4);
  float* cvec = (float*)alloc((size_t)N * 8 * 4);
  float* buf0 = (float*)alloc((size_t)N * HID * 4);
  float* buf1 = (float*)alloc((size_t)N * HID * 4);
  size_t base_cursor = cursor;
  __hip_bfloat16* hb = (__hip_bfloat16*)alloc((size_t)N * HID * 2);
  bool use_bf16 = (cursor <= ws_size);
  if (!use_bf16) {
    hb = nullptr;
    if (base_cursor > ws_size) return;
  }

  long long expect = (long long)E / (nbin > 0 ? nbin : 1);
  int CAPB = (int)((((expect * 5) / 4 + 127) / 64) * 64);
  if (CAPB < 256) CAPB = 256;
  size_t bdata_bytes = (size_t)nbin * CAPB * 4;
  bool use_radix = (N <= (1 << SBITS)) && (nbin <= 1024) &&
                   (bdata_bytes <= (size_t)N * HID * 4);
  uint32_t* bdata = (uint32_t*)buf1;  // staging aliases buf1 (dead until layer-1 agg)

  int nThreadsN = (N + 255) / 256;

  hipMemsetAsync(flags, 0, 16, stream);
  detect_mask_kernel<<<256, 256, 0, stream>>>((const unsigned char*)maskp, N, N / 4, flags);

  if (use_radix) {
    init_gcur_kernel<<<(nbin + 255) / 256, 256, 0, stream>>>(gcur, nbin, CAPB);
    radixA_kernel<<<(E + MCHUNK - 1) / MCHUNK, 256, 0, stream>>>(srcp, dstp, gcur, bdata,
                                                                 nbin, CAPB, E);
    bucket_meta_kernel<<<1, 256, 0, stream>>>(gcur, bstart, nbin, CAPB);
    radixB_kernel<<<nbin, 256, 0, stream>>>(bdata, gcur, bstart, CAPB, off, dis, csr, N, E);
  } else {
    hipMemsetAsync(cnt, 0, (size_t)N * 4, stream);
    int nb = (N + 1023) / 1024;
    hist_part_kernel<<<NPART * NCHUNK, 256, 0, stream>>>(dstp, cnt, E, N);
    scan1_kernel<<<nb, 256, 0, stream>>>(cnt, off, bsum, dis, N);
    scan2_kernel<<<1, 64, 0, stream>>>(bsum, nb);
    scan3_kernel<<<nThreadsN, 256, 0, stream>>>(off, bsum, cnt, N, E);
    fill_part_kernel<<<NPART * NCHUNK, 256, 0, stream>>>(srcp, dstp, cnt, csr, E, N);
  }

  expand_mask_h0<<<nThreadsN, 256, 0, stream>>>(maskp, (const float4*)x, flags, dis,
                                                out + (size_t)N * 4, cvec, (float4*)h0s, N);

  // layer 0
  l0_agg_kernel<<<nThreadsN, 256, 0, stream>>>((const float4*)h0s, dis, off, csr, cvec, N);
  l0_combine_kernel<<<(N * HID + 255) / 256, 256, 0, stream>>>(cvec, W0, b0, resW, resb, dis,
                                                               buf0, hb);

  // layer 1: agg(h1) -> buf1 ; h2 = relu(buf1@W1 + b1 + buf0) -> buf1 (+ hb)
  if (use_bf16)
    agg_hid_bf16_kernel<<<(N + 3) / 4, 256, 0, stream>>>((const uint32_t*)hb, dis, off, csr, buf1, N);
  else
    agg_hid_kernel<<<(N + 3) / 4, 256, 0, stream>>>(buf0, dis, off, csr, buf1, N);
  gemm_resid_relu_kernel<<<(N + 63) / 64, 256, 0, stream>>>(buf1, buf0, W1, b1, dis, hb, N);

  // layer 2: agg(h2) -> buf0 ; fused gemm+residual+relu+fc -> out (h3 stays on-chip)
  if (use_bf16)
    agg_hid_bf16_kernel<<<(N + 3) / 4, 256, 0, stream>>>((const uint32_t*)hb, dis, off, csr, buf0, N);
  else
    agg_hid_kernel<<<(N + 3) / 4, 256, 0, stream>>>(buf1, dis, off, csr, buf0, N);
  gemm_resid_fc_kernel<<<(N + 63) / 64, 256, 0, stream>>>(buf0, buf1, W2, b2, fcW, fcb, out, N);
}

// Round 9
// 539.017 us; speedup vs baseline: 1.4639x; 1.0308x over previous
//
#include <hip/hip_runtime.h>
#include <hip/hip_bf16.h>
#include <stdint.h>

#define HID 128
#define NPART 8
#define NCHUNK 256
#define MCHUNK 4096   // edges per radixA block
#define LBITS 10      // local dst bits; bucket = dst>>LBITS
#define SBITS 22      // src bits in packed word (N must be <= 1<<22)

// ---------------- mask storage detection ----------------
__global__ void detect_mask_kernel(const unsigned char* __restrict__ p, int nbytes,
                                   int nfloat, int* __restrict__ flags) {
  int stride = blockDim.x * gridDim.x;
  for (int i = blockIdx.x * blockDim.x + threadIdx.x; i < nbytes; i += stride) {
    if ((i & 3) && p[i] != 0) { atomicOr(&flags[0], 1); break; }
  }
  const float* fp = (const float*)p;
  for (int i = blockIdx.x * blockDim.x + threadIdx.x; i < nfloat; i += stride) {
    float f = fp[i];
    if (!(f == 0.0f || f == 1.0f)) { atomicOr(&flags[1], 1); break; }
  }
}

__global__ void expand_mask_h0(const void* __restrict__ maskp, const float4* __restrict__ x4,
                               const int* __restrict__ flags, const float* __restrict__ dis,
                               float* __restrict__ maskout, float* __restrict__ cvec,
                               float4* __restrict__ h0s, int N) {
  int i = blockIdx.x * blockDim.x + threadIdx.x;
  if (i >= N) return;
  float m;
  if (flags[0] == 0)      m = (((const int*)maskp)[i] != 0) ? 1.f : 0.f;
  else if (flags[1] == 0) m = (((const float*)maskp)[i] != 0.f) ? 1.f : 0.f;
  else                    m = (((const unsigned char*)maskp)[i] != 0) ? 1.f : 0.f;
  maskout[i] = m;
  float4 xv = x4[i];
  float4 h0 = make_float4(m * xv.x, m * xv.y, m * xv.z, m * xv.w);
  float* cv = cvec + (size_t)i * 8;
  cv[4] = h0.x; cv[5] = h0.y; cv[6] = h0.z; cv[7] = h0.w;
  float d = dis[i];
  h0s[i] = make_float4(d * h0.x, d * h0.y, d * h0.z, d * h0.w);
}

// ---------------- CSR build: two-pass LDS-staged radix ----------------
__global__ void init_gcur_kernel(int* __restrict__ gcur, int n, int CAPB) {
  int i = blockIdx.x * blockDim.x + threadIdx.x;
  if (i < n) gcur[i] = i * CAPB;
}

__global__ void radixA_kernel(const int* __restrict__ src, const int* __restrict__ dst,
                              int* __restrict__ gcur, uint32_t* __restrict__ bdata,
                              int nbin, int CAPB, int E) {
  __shared__ uint32_t sv[MCHUNK];
  __shared__ uint16_t sb[MCHUNK];
  __shared__ int bcnt[1024], boff[1024], gbase[1024];
  __shared__ int wsum[4];
  int t = threadIdx.x;
  int base = blockIdx.x * MCHUNK;
  int m = E - base; if (m > MCHUNK) m = MCHUNK;
  for (int i = t; i < 1024; i += 256) bcnt[i] = 0;
  __syncthreads();
  uint32_t pk[16]; short bn[16];
#pragma unroll
  for (int j = 0; j < 16; j++) {
    int i = base + t + j * 256;
    if (i < base + m) {
      int d = __builtin_nontemporal_load(&dst[i]);
      int s = __builtin_nontemporal_load(&src[i]);
      int b = d >> LBITS;
      pk[j] = ((uint32_t)(d & ((1 << LBITS) - 1)) << SBITS) | (uint32_t)s;
      bn[j] = (short)b;
      atomicAdd(&bcnt[b], 1);
    } else bn[j] = -1;
  }
  __syncthreads();
  {
    int lane = t & 63, w = t >> 6, i0 = t * 4;
    int v0 = bcnt[i0], v1 = bcnt[i0 + 1], v2 = bcnt[i0 + 2], v3 = bcnt[i0 + 3];
    int ts = v0 + v1 + v2 + v3, sc = ts;
    for (int d = 1; d < 64; d <<= 1) { int x = __shfl_up(sc, d, 64); if (lane >= d) sc += x; }
    if (lane == 63) wsum[w] = sc;
    __syncthreads();
    int wo = 0;
    for (int k = 0; k < w; k++) wo += wsum[k];
    int excl = wo + sc - ts;
    boff[i0] = excl; boff[i0 + 1] = excl + v0;
    boff[i0 + 2] = excl + v0 + v1; boff[i0 + 3] = excl + v0 + v1 + v2;
  }
  __syncthreads();
  for (int i = t; i < nbin; i += 256) {
    int c = bcnt[i];
    gbase[i] = c ? atomicAdd(&gcur[i], c) : 0;
  }
  __syncthreads();
  for (int i = t; i < nbin; i += 256) bcnt[i] = boff[i];
  __syncthreads();
#pragma unroll
  for (int j = 0; j < 16; j++) {
    if (bn[j] >= 0) {
      int p = atomicAdd(&bcnt[bn[j]], 1);
      sv[p] = pk[j];
      sb[p] = (uint16_t)bn[j];
    }
  }
  __syncthreads();
  for (int i = t; i < m; i += 256) {
    int b = sb[i];
    int gp = gbase[b] + (i - boff[b]);
    if (gp < (b + 1) * CAPB) bdata[gp] = sv[i];
  }
}

// fused btot + scan (single block, nbin <= 1024)
__global__ void bucket_meta_kernel(const int* __restrict__ gcur, int* __restrict__ bstart,
                                   int nbin, int CAPB) {
  __shared__ int wsum[4];
  int t = threadIdx.x, lane = t & 63, w = t >> 6, i0 = t * 4;
  int v[4];
#pragma unroll
  for (int q = 0; q < 4; q++) {
    int i = i0 + q;
    int c = 0;
    if (i < nbin) {
      c = gcur[i] - i * CAPB;
      if (c > CAPB) c = CAPB;
    }
    v[q] = c;
  }
  int ts = v[0] + v[1] + v[2] + v[3], sc = ts;
  for (int d = 1; d < 64; d <<= 1) { int x = __shfl_up(sc, d, 64); if (lane >= d) sc += x; }
  if (lane == 63) wsum[w] = sc;
  __syncthreads();
  int wo = 0;
  for (int k = 0; k < w; k++) wo += wsum[k];
  int excl = wo + sc - ts;
  int e[4] = {excl, excl + v[0], excl + v[0] + v[1], excl + v[0] + v[1] + v[2]};
#pragma unroll
  for (int q = 0; q < 4; q++)
    if (i0 + q < nbin) bstart[i0 + q] = e[q];
  if (t == 255) bstart[nbin] = wo + sc;
}

__global__ void radixB_kernel(const uint32_t* __restrict__ bdata, const int* __restrict__ gcur,
                              const int* __restrict__ bstart, int CAPB,
                              int* __restrict__ off, float* __restrict__ dis,
                              int* __restrict__ csr, int N, int E) {
  __shared__ int cnt[1024], loff[1024];
  __shared__ int wsum[4];
  int b = blockIdx.x, t = threadIdx.x;
  int cb = gcur[b] - b * CAPB; if (cb > CAPB) cb = CAPB;
  int gb = bstart[b];
  const uint32_t* bd = bdata + (size_t)b * CAPB;
  for (int i = t; i < 1024; i += 256) cnt[i] = 0;
  __syncthreads();
  for (int i = t; i < cb; i += 256) atomicAdd(&cnt[bd[i] >> SBITS], 1);
  __syncthreads();
  {
    int lane = t & 63, w = t >> 6, i0 = t * 4;
    int v0 = cnt[i0], v1 = cnt[i0 + 1], v2 = cnt[i0 + 2], v3 = cnt[i0 + 3];
    int ts = v0 + v1 + v2 + v3, sc = ts;
    for (int d = 1; d < 64; d <<= 1) { int x = __shfl_up(sc, d, 64); if (lane >= d) sc += x; }
    if (lane == 63) wsum[w] = sc;
    __syncthreads();
    int wo = 0;
    for (int k = 0; k < w; k++) wo += wsum[k];
    int e0 = wo + sc - ts;
    int e1 = e0 + v0, e2 = e1 + v1, e3 = e2 + v2;
    loff[i0] = e0; loff[i0 + 1] = e1; loff[i0 + 2] = e2; loff[i0 + 3] = e3;
    int d0 = b * 1024 + i0;
    if (d0 + 0 < N) { off[d0 + 0] = gb + e0; dis[d0 + 0] = rsqrtf((float)v0 + 1.0f); }
    if (d0 + 1 < N) { off[d0 + 1] = gb + e1; dis[d0 + 1] = rsqrtf((float)v1 + 1.0f); }
    if (d0 + 2 < N) { off[d0 + 2] = gb + e2; dis[d0 + 2] = rsqrtf((float)v2 + 1.0f); }
    if (d0 + 3 < N) { off[d0 + 3] = gb + e3; dis[d0 + 3] = rsqrtf((float)v3 + 1.0f); }
  }
  if (b == 0 && t == 0) off[N] = E;
  __syncthreads();
  for (int i = t; i < 1024; i += 256) cnt[i] = loff[i];
  __syncthreads();
  for (int i = t; i < cb; i += 256) {
    uint32_t v = bd[i];
    int p = atomicAdd(&cnt[v >> SBITS], 1);
    csr[gb + p] = (int)(v & ((1u << SBITS) - 1));
  }
}

// ---------------- scan machinery (fallback path) ----------------
__global__ void scan1_kernel(const int* __restrict__ cnt, int* __restrict__ off,
                             int* __restrict__ bsum, float* __restrict__ dis, int N) {
  __shared__ int wsum[4];
  int t = threadIdx.x, lane = t & 63, w = t >> 6;
  int base = blockIdx.x * 1024 + t * 4;
  int v0 = (base + 0 < N) ? cnt[base + 0] : 0;
  int v1 = (base + 1 < N) ? cnt[base + 1] : 0;
  int v2 = (base + 2 < N) ? cnt[base + 2] : 0;
  int v3 = (base + 3 < N) ? cnt[base + 3] : 0;
  if (dis) {
    if (base + 0 < N) dis[base + 0] = rsqrtf((float)v0 + 1.0f);
    if (base + 1 < N) dis[base + 1] = rsqrtf((float)v1 + 1.0f);
    if (base + 2 < N) dis[base + 2] = rsqrtf((float)v2 + 1.0f);
    if (base + 3 < N) dis[base + 3] = rsqrtf((float)v3 + 1.0f);
  }
  int ts = v0 + v1 + v2 + v3;
  int sc = ts;
  for (int d = 1; d < 64; d <<= 1) {
    int x = __shfl_up(sc, d, 64);
    if (lane >= d) sc += x;
  }
  if (lane == 63) wsum[w] = sc;
  __syncthreads();
  int wo = 0;
  for (int i = 0; i < w; i++) wo += wsum[i];
  int excl = wo + sc - ts;
  if (base + 0 < N) off[base + 0] = excl;
  if (base + 1 < N) off[base + 1] = excl + v0;
  if (base + 2 < N) off[base + 2] = excl + v0 + v1;
  if (base + 3 < N) off[base + 3] = excl + v0 + v1 + v2;
  if (t == 255) bsum[blockIdx.x] = wo + sc;
}

__global__ void scan2_kernel(int* __restrict__ bsum, int nb) {
  if (threadIdx.x == 0 && blockIdx.x == 0) {
    int run = 0;
    for (int i = 0; i < nb; i++) { int v = bsum[i]; bsum[i] = run; run += v; }
  }
}

__global__ void scan3_kernel(int* __restrict__ off, const int* __restrict__ bsum,
                             int* __restrict__ cur, int N, int E) {
  int i = blockIdx.x * blockDim.x + threadIdx.x;
  if (i < N) {
    int o = off[i] + bsum[i >> 10];
    off[i] = o;
    if (cur) cur[i] = o;
  }
  if (i == 0) off[N] = E;
}

__global__ void hist_part_kernel(const int* __restrict__ dst, int* __restrict__ cnt,
                                 int E, int N) {
  int p = blockIdx.x & (NPART - 1);
  int chunk = blockIdx.x >> 3;
  int lo = (int)((long long)p * N / NPART);
  int hi = (int)((long long)(p + 1) * N / NPART);
  int stride = NCHUNK * 256;
  for (int e = chunk * 256 + threadIdx.x; e < E; e += stride) {
    int d = __builtin_nontemporal_load(&dst[e]);
    if (d >= lo && d < hi) atomicAdd(&cnt[d], 1);
  }
}

__global__ void fill_part_kernel(const int* __restrict__ src, const int* __restrict__ dst,
                                 int* __restrict__ cur, int* __restrict__ csr, int E, int N) {
  int p = blockIdx.x & (NPART - 1);
  int chunk = blockIdx.x >> 3;
  int lo = (int)((long long)p * N / NPART);
  int hi = (int)((long long)(p + 1) * N / NPART);
  int stride = NCHUNK * 256;
  for (int e = chunk * 256 + threadIdx.x; e < E; e += stride) {
    int d = __builtin_nontemporal_load(&dst[e]);
    if (d >= lo && d < hi) {
      int s = __builtin_nontemporal_load(&src[e]);
      int pos = atomicAdd(&cur[d], 1);
      csr[pos] = s;
    }
  }
}

// ---------------- layer 0 aggregation (int4 broadcast csr loads) ----------------
__global__ void l0_agg_kernel(const float4* __restrict__ h0s, const float* __restrict__ dis,
                              const int* __restrict__ off, const int* __restrict__ csr,
                              float* __restrict__ cvec, int N) {
  int n = blockIdx.x * blockDim.x + threadIdx.x;
  if (n >= N) return;
  float4 a = h0s[n];
  int e0 = off[n], e1 = off[n + 1];
  int i = e0;
  for (; i < e1 && (i & 3); i++) {
    float4 v = h0s[csr[i]];
    a.x += v.x; a.y += v.y; a.z += v.z; a.w += v.w;
  }
  for (; i + 4 <= e1; i += 4) {
    int4 c = *(const int4*)&csr[i];
    float4 v0 = h0s[c.x], v1 = h0s[c.y], v2 = h0s[c.z], v3 = h0s[c.w];
    a.x += v0.x + v1.x + v2.x + v3.x;
    a.y += v0.y + v1.y + v2.y + v3.y;
    a.z += v0.z + v1.z + v2.z + v3.z;
    a.w += v0.w + v1.w + v2.w + v3.w;
  }
  for (; i < e1; i++) {
    float4 v = h0s[csr[i]];
    a.x += v.x; a.y += v.y; a.z += v.z; a.w += v.w;
  }
  float dn = dis[n];
  float* cv = cvec + (size_t)n * 8;
  cv[0] = dn * a.x; cv[1] = dn * a.y; cv[2] = dn * a.z; cv[3] = dn * a.w;
}

__global__ void l0_combine_kernel(const float* __restrict__ cvec, const float* __restrict__ W0,
                                  const float* __restrict__ b0, const float* __restrict__ resW,
                                  const float* __restrict__ resb, const float* __restrict__ dis,
                                  float* __restrict__ h1, __hip_bfloat16* __restrict__ hbout) {
  int idx = blockIdx.x * blockDim.x + threadIdx.x;
  int n = idx >> 7, c = idx & 127;
  const float* cv = cvec + (size_t)n * 8;
  float acc = b0[c] + resb[c];
#pragma unroll
  for (int k = 0; k < 4; k++) {
    acc += cv[k] * W0[k * HID + c];
    acc += cv[4 + k] * resW[k * HID + c];
  }
  float v = fmaxf(acc, 0.0f);
  h1[idx] = v;
  if (hbout) hbout[idx] = __float2bfloat16(dis[n] * v);
}

// ---------------- 128-dim aggregation: bf16 gather -> bf16 out, int4 csr loads ----------------
#define ACC1(W) { a0 += __uint_as_float((W) << 16); a1 += __uint_as_float((W) & 0xffff0000u); }
__global__ void agg_hid_bf16_kernel(const uint32_t* __restrict__ hb, const float* __restrict__ dis,
                                    const int* __restrict__ off, const int* __restrict__ csr,
                                    uint32_t* __restrict__ aggout, int N) {
  int node = blockIdx.x * 4 + (threadIdx.x >> 6);
  int lane = threadIdx.x & 63;
  if (node >= N) return;
  uint32_t w = hb[(size_t)node * 64 + lane];
  float a0 = __uint_as_float(w << 16);
  float a1 = __uint_as_float(w & 0xffff0000u);
  int e0 = off[node], e1 = off[node + 1];
  int i = e0;
  for (; i < e1 && (i & 3); i++) {
    uint32_t ww = hb[(size_t)csr[i] * 64 + lane];
    ACC1(ww)
  }
  for (; i + 8 <= e1; i += 8) {
    int4 c0 = *(const int4*)&csr[i];
    int4 c1 = *(const int4*)&csr[i + 4];
    uint32_t w0 = hb[(size_t)c0.x * 64 + lane];
    uint32_t w1 = hb[(size_t)c0.y * 64 + lane];
    uint32_t w2 = hb[(size_t)c0.z * 64 + lane];
    uint32_t w3 = hb[(size_t)c0.w * 64 + lane];
    uint32_t w4 = hb[(size_t)c1.x * 64 + lane];
    uint32_t w5 = hb[(size_t)c1.y * 64 + lane];
    uint32_t w6 = hb[(size_t)c1.z * 64 + lane];
    uint32_t w7 = hb[(size_t)c1.w * 64 + lane];
    ACC1(w0) ACC1(w1) ACC1(w2) ACC1(w3) ACC1(w4) ACC1(w5) ACC1(w6) ACC1(w7)
  }
  for (; i + 4 <= e1; i += 4) {
    int4 c = *(const int4*)&csr[i];
    uint32_t w0 = hb[(size_t)c.x * 64 + lane];
    uint32_t w1 = hb[(size_t)c.y * 64 + lane];
    uint32_t w2 = hb[(size_t)c.z * 64 + lane];
    uint32_t w3 = hb[(size_t)c.w * 64 + lane];
    ACC1(w0) ACC1(w1) ACC1(w2) ACC1(w3)
  }
  for (; i < e1; i++) {
    uint32_t ww = hb[(size_t)csr[i] * 64 + lane];
    ACC1(ww)
  }
  float dn = dis[node];
  __hip_bfloat162 p = __float22bfloat162_rn(make_float2(dn * a0, dn * a1));
  aggout[(size_t)node * 64 + lane] = *(uint32_t*)&p;
}

// f32 fallback aggregation (ws too small for bf16 buffers)
__global__ void agg_hid_kernel(const float* __restrict__ h, const float* __restrict__ dis,
                               const int* __restrict__ off, const int* __restrict__ csr,
                               float* __restrict__ out, int N) {
  int node = blockIdx.x * 4 + (threadIdx.x >> 6);
  int lane = threadIdx.x & 63;
  if (node >= N) return;
  float dn = dis[node];
  const float* hrow = h + (size_t)node * HID;
  float a0 = dn * hrow[lane];
  float a1 = dn * hrow[lane + 64];
  int e0 = off[node], e1 = off[node + 1];
  for (int i = e0; i < e1; i++) {
    int s = csr[i];
    float d = dis[s];
    const float* hs = h + (size_t)s * HID;
    a0 += d * hs[lane];
    a1 += d * hs[lane + 64];
  }
  out[(size_t)node * HID + lane] = dn * a0;
  out[(size_t)node * HID + lane + 64] = dn * a1;
}

// ---------------- h_next = relu(agg @ W + b + h_res); agg may be bf16x2 or f32 ----------------
__global__ void gemm_resid_relu_kernel(const void* __restrict__ agp, int agBf16,
                                       float* __restrict__ hout,
                                       const float* __restrict__ hres,
                                       const float* __restrict__ W, const float* __restrict__ b,
                                       const float* __restrict__ dis,
                                       __hip_bfloat16* __restrict__ hbout, int N) {
  __shared__ float ash[64 * HID];
  int t = threadIdx.x;
  int n0 = blockIdx.x * 64;
  if (agBf16) {
    const uint32_t* agb = (const uint32_t*)agp;
    for (int i = t; i < 64 * 64; i += 256) {
      int gn = n0 + (i >> 6);
      uint32_t w = (gn < N) ? agb[(size_t)gn * 64 + (i & 63)] : 0u;
      ash[(i >> 6) * HID + (i & 63) * 2]     = __uint_as_float(w << 16);
      ash[(i >> 6) * HID + (i & 63) * 2 + 1] = __uint_as_float(w & 0xffff0000u);
    }
  } else {
    const float* agf = (const float*)agp;
    for (int i = t; i < 64 * HID; i += 256) {
      int gn = n0 + (i >> 7);
      ash[i] = (gn < N) ? agf[(size_t)gn * HID + (i & 127)] : 0.0f;
    }
  }
  __syncthreads();
  int tc = t & 31;
  int tn = t >> 5;
  float acc[8][4];
#pragma unroll
  for (int j = 0; j < 8; j++)
#pragma unroll
    for (int q = 0; q < 4; q++) acc[j][q] = 0.0f;

  for (int k = 0; k < HID; k += 4) {
    float4 w0 = *(const float4*)&W[(k + 0) * HID + tc * 4];
    float4 w1 = *(const float4*)&W[(k + 1) * HID + tc * 4];
    float4 w2 = *(const float4*)&W[(k + 2) * HID + tc * 4];
    float4 w3 = *(const float4*)&W[(k + 3) * HID + tc * 4];
#pragma unroll
    for (int j = 0; j < 8; j++) {
      float4 a = *(const float4*)&ash[(tn * 8 + j) * HID + k];
      acc[j][0] += a.x * w0.x + a.y * w1.x + a.z * w2.x + a.w * w3.x;
      acc[j][1] += a.x * w0.y + a.y * w1.y + a.z * w2.y + a.w * w3.y;
      acc[j][2] += a.x * w0.z + a.y * w1.z + a.z * w2.z + a.w * w3.z;
      acc[j][3] += a.x * w0.w + a.y * w1.w + a.z * w2.w + a.w * w3.w;
    }
  }
  float4 bv = *(const float4*)&b[tc * 4];
#pragma unroll
  for (int j = 0; j < 8; j++) {
    int gn = n0 + tn * 8 + j;
    if (gn < N) {
      float4 hv = *(const float4*)&hres[(size_t)gn * HID + tc * 4];
      float4 o;
      o.x = fmaxf(acc[j][0] + bv.x + hv.x, 0.0f);
      o.y = fmaxf(acc[j][1] + bv.y + hv.y, 0.0f);
      o.z = fmaxf(acc[j][2] + bv.z + hv.z, 0.0f);
      o.w = fmaxf(acc[j][3] + bv.w + hv.w, 0.0f);
      *(float4*)&hout[(size_t)gn * HID + tc * 4] = o;
      if (hbout) {
        float dnn = dis[gn];
        __hip_bfloat162 p01 = __float22bfloat162_rn(make_float2(dnn * o.x, dnn * o.y));
        __hip_bfloat162 p23 = __float22bfloat162_rn(make_float2(dnn * o.z, dnn * o.w));
        *(__hip_bfloat162*)&hbout[(size_t)gn * HID + tc * 4] = p01;
        *(__hip_bfloat162*)&hbout[(size_t)gn * HID + tc * 4 + 2] = p23;
      }
    }
  }
}

// ---------------- layer 2 fused: h3 = relu(agg@W + b + hres); out = h3@fcW + fcb ----------------
__global__ void gemm_resid_fc_kernel(const void* __restrict__ agp, int agBf16,
                                     const float* __restrict__ hres,
                                     const float* __restrict__ W, const float* __restrict__ b,
                                     const float* __restrict__ fcW, const float* __restrict__ fcb,
                                     float* __restrict__ out, int N) {
  __shared__ float ash[64 * HID];
  int t = threadIdx.x;
  int n0 = blockIdx.x * 64;
  if (agBf16) {
    const uint32_t* agb = (const uint32_t*)agp;
    for (int i = t; i < 64 * 64; i += 256) {
      int gn = n0 + (i >> 6);
      uint32_t w = (gn < N) ? agb[(size_t)gn * 64 + (i & 63)] : 0u;
      ash[(i >> 6) * HID + (i & 63) * 2]     = __uint_as_float(w << 16);
      ash[(i >> 6) * HID + (i & 63) * 2 + 1] = __uint_as_float(w & 0xffff0000u);
    }
  } else {
    const float* agf = (const float*)agp;
    for (int i = t; i < 64 * HID; i += 256) {
      int gn = n0 + (i >> 7);
      ash[i] = (gn < N) ? agf[(size_t)gn * HID + (i & 127)] : 0.0f;
    }
  }
  __syncthreads();
  int tc = t & 31;
  int tn = t >> 5;
  float acc[8][4];
#pragma unroll
  for (int j = 0; j < 8; j++)
#pragma unroll
    for (int q = 0; q < 4; q++) acc[j][q] = 0.0f;

  for (int k = 0; k < HID; k += 4) {
    float4 w0 = *(const float4*)&W[(k + 0) * HID + tc * 4];
    float4 w1 = *(const float4*)&W[(k + 1) * HID + tc * 4];
    float4 w2 = *(const float4*)&W[(k + 2) * HID + tc * 4];
    float4 w3 = *(const float4*)&W[(k + 3) * HID + tc * 4];
#pragma unroll
    for (int j = 0; j < 8; j++) {
      float4 a = *(const float4*)&ash[(tn * 8 + j) * HID + k];
      acc[j][0] += a.x * w0.x + a.y * w1.x + a.z * w2.x + a.w * w3.x;
      acc[j][1] += a.x * w0.y + a.y * w1.y + a.z * w2.y + a.w * w3.y;
      acc[j][2] += a.x * w0.z + a.y * w1.z + a.z * w2.z + a.w * w3.z;
      acc[j][3] += a.x * w0.w + a.y * w1.w + a.z * w2.w + a.w * w3.w;
    }
  }
  float4 f0 = *(const float4*)&fcW[(tc * 4 + 0) * 4];
  float4 f1 = *(const float4*)&fcW[(tc * 4 + 1) * 4];
  float4 f2 = *(const float4*)&fcW[(tc * 4 + 2) * 4];
  float4 f3 = *(const float4*)&fcW[(tc * 4 + 3) * 4];
  float4 bv = *(const float4*)&b[tc * 4];
  float4 fb = *(const float4*)&fcb[0];
#pragma unroll
  for (int j = 0; j < 8; j++) {
    int gn = n0 + tn * 8 + j;
    float4 o = make_float4(0.f, 0.f, 0.f, 0.f);
    if (gn < N) {
      float4 hv = *(const float4*)&hres[(size_t)gn * HID + tc * 4];
      o.x = fmaxf(acc[j][0] + bv.x + hv.x, 0.0f);
      o.y = fmaxf(acc[j][1] + bv.y + hv.y, 0.0f);
      o.z = fmaxf(acc[j][2] + bv.z + hv.z, 0.0f);
      o.w = fmaxf(acc[j][3] + bv.w + hv.w, 0.0f);
    }
    float r0 = o.x * f0.x + o.y * f1.x + o.z * f2.x + o.w * f3.x;
    float r1 = o.x * f0.y + o.y * f1.y + o.z * f2.y + o.w * f3.y;
    float r2 = o.x * f0.z + o.y * f1.z + o.z * f2.z + o.w * f3.z;
    float r3 = o.x * f0.w + o.y * f1.w + o.z * f2.w + o.w * f3.w;
#pragma unroll
    for (int d = 1; d < 32; d <<= 1) {
      r0 += __shfl_xor(r0, d, 64);
      r1 += __shfl_xor(r1, d, 64);
      r2 += __shfl_xor(r2, d, 64);
      r3 += __shfl_xor(r3, d, 64);
    }
    if (tc == 0 && gn < N)
      *(float4*)&out[(size_t)gn * 4] =
          make_float4(r0 + fb.x, r1 + fb.y, r2 + fb.z, r3 + fb.w);
  }
}

// ---------------- host ----------------
extern "C" void kernel_launch(void* const* d_in, const int* in_sizes, int n_in,
                              void* d_out, int out_size, void* d_ws, size_t ws_size,
                              hipStream_t stream) {
  const float* x = (const float*)d_in[0];
  const int* edge = (const int*)d_in[1];
  const void* maskp = d_in[2];
  const float* W0 = (const float*)d_in[3];
  const float* b0 = (const float*)d_in[4];
  const float* resW = (const float*)d_in[5];
  const float* resb = (const float*)d_in[6];
  const float* W1 = (const float*)d_in[7];
  const float* b1 = (const float*)d_in[8];
  const float* W2 = (const float*)d_in[9];
  const float* b2 = (const float*)d_in[10];
  const float* fcW = (const float*)d_in[11];
  const float* fcb = (const float*)d_in[12];
  float* out = (float*)d_out;

  int N = in_sizes[0] / 4;
  int E = in_sizes[1] / 2;
  const int* srcp = edge;
  const int* dstp = edge + E;

  char* ws = (char*)d_ws;
  size_t cursor = 0;
  auto alloc = [&](size_t bytes) { char* p = ws + cursor; cursor += (bytes + 511) & ~(size_t)511; return p; };
  int* flags = (int*)alloc(16);
  int* cnt = (int*)alloc((size_t)N * 4);   // fallback path only
  float* dis = (float*)alloc((size_t)N * 4);
  int* off = (int*)alloc((size_t)(N + 1) * 4);
  int* bsum = (int*)alloc(1024);
  int nbin = (N + 1023) >> 10;
  int* gcur = (int*)alloc((size_t)(nbin + 1) * 4);
  int* bstart = (int*)alloc((size_t)(nbin + 1) * 4);
  int* csr = (int*)alloc((size_t)E * 4);
  float* h0s = (float*)alloc((size_t)N * 4 * 4);
  float* cvec = (float*)alloc((size_t)N * 8 * 4);
  float* buf0 = (float*)alloc((size_t)N * HID * 4);
  float* buf1 = (float*)alloc((size_t)N * HID * 4);
  size_t base_cursor = cursor;
  __hip_bfloat16* hb = (__hip_bfloat16*)alloc((size_t)N * HID * 2);
  uint32_t* aggbf = (uint32_t*)alloc((size_t)N * 64 * 4);
  bool use_bf16 = (cursor <= ws_size);   // bf16 gather + bf16 agg intermediates
  if (!use_bf16) {
    hb = nullptr;
    aggbf = nullptr;
    if (base_cursor > ws_size) return;
  }

  long long expect = (long long)E / (nbin > 0 ? nbin : 1);
  int CAPB = (int)((((expect * 5) / 4 + 127) / 64) * 64);
  if (CAPB < 256) CAPB = 256;
  size_t bdata_bytes = (size_t)nbin * CAPB * 4;
  bool use_radix = (N <= (1 << SBITS)) && (nbin <= 1024) &&
                   (bdata_bytes <= (size_t)N * HID * 4);
  uint32_t* bdata = (uint32_t*)buf1;  // staging aliases buf1 (dead until layer-1 gemm writes)

  int nThreadsN = (N + 255) / 256;

  hipMemsetAsync(flags, 0, 16, stream);
  detect_mask_kernel<<<256, 256, 0, stream>>>((const unsigned char*)maskp, N, N / 4, flags);

  if (use_radix) {
    init_gcur_kernel<<<(nbin + 255) / 256, 256, 0, stream>>>(gcur, nbin, CAPB);
    radixA_kernel<<<(E + MCHUNK - 1) / MCHUNK, 256, 0, stream>>>(srcp, dstp, gcur, bdata,
                                                                 nbin, CAPB, E);
    bucket_meta_kernel<<<1, 256, 0, stream>>>(gcur, bstart, nbin, CAPB);
    radixB_kernel<<<nbin, 256, 0, stream>>>(bdata, gcur, bstart, CAPB, off, dis, csr, N, E);
  } else {
    hipMemsetAsync(cnt, 0, (size_t)N * 4, stream);
    int nb = (N + 1023) / 1024;
    hist_part_kernel<<<NPART * NCHUNK, 256, 0, stream>>>(dstp, cnt, E, N);
    scan1_kernel<<<nb, 256, 0, stream>>>(cnt, off, bsum, dis, N);
    scan2_kernel<<<1, 64, 0, stream>>>(bsum, nb);
    scan3_kernel<<<nThreadsN, 256, 0, stream>>>(off, bsum, cnt, N, E);
    fill_part_kernel<<<NPART * NCHUNK, 256, 0, stream>>>(srcp, dstp, cnt, csr, E, N);
  }

  expand_mask_h0<<<nThreadsN, 256, 0, stream>>>(maskp, (const float4*)x, flags, dis,
                                                out + (size_t)N * 4, cvec, (float4*)h0s, N);

  // layer 0
  l0_agg_kernel<<<nThreadsN, 256, 0, stream>>>((const float4*)h0s, dis, off, csr, cvec, N);
  l0_combine_kernel<<<(N * HID + 255) / 256, 256, 0, stream>>>(cvec, W0, b0, resW, resb, dis,
                                                               buf0, hb);

  if (use_bf16) {
    // layer 1: agg(hb) -> aggbf (bf16) ; h2 = relu(aggbf@W1 + b1 + buf0) -> buf1 (+ hb)
    agg_hid_bf16_kernel<<<(N + 3) / 4, 256, 0, stream>>>((const uint32_t*)hb, dis, off, csr,
                                                         aggbf, N);
    gemm_resid_relu_kernel<<<(N + 63) / 64, 256, 0, stream>>>(aggbf, 1, buf1, buf0, W1, b1,
                                                              dis, hb, N);
    // layer 2: agg(hb) -> aggbf ; fused gemm+residual+relu+fc -> out
    agg_hid_bf16_kernel<<<(N + 3) / 4, 256, 0, stream>>>((const uint32_t*)hb, dis, off, csr,
                                                         aggbf, N);
    gemm_resid_fc_kernel<<<(N + 63) / 64, 256, 0, stream>>>(aggbf, 1, buf1, W2, b2,
                                                            fcW, fcb, out, N);
  } else {
    // f32 fallback
    agg_hid_kernel<<<(N + 3) / 4, 256, 0, stream>>>(buf0, dis, off, csr, buf1, N);
    gemm_resid_relu_kernel<<<(N + 63) / 64, 256, 0, stream>>>(buf1, 0, buf1, buf0, W1, b1,
                                                              dis, nullptr, N);
    agg_hid_kernel<<<(N + 3) / 4, 256, 0, stream>>>(buf1, dis, off, csr, buf0, N);
    gemm_resid_fc_kernel<<<(N + 63) / 64, 256, 0, stream>>>(buf0, 0, buf1, W2, b2,
                                                            fcW, fcb, out, N);
  }
}